// Round 7
// baseline (787.611 us; speedup 1.0000x reference)
//
#include <hip/hip_runtime.h>
#include <math.h>

// ExpressionPerformer: B=16,G=2048,D=256,H=8,dh=32,FFN=1024,L=4
// Round-16: ffn_fused = 2 blocks/CU with R12's SPILL-FREE register profile.
//  - A strip (64 rows, 32KB) staged to LDS via gld16 (compact 64-row layout),
//    fragments re-read from LDS per step (R12-proven: no spill at ~96
//    persistent regs). NO A-in-registers (R13-R15 all spilled on that).
//  - 2-slot weight pipeline (weights are L2-hot; slack = 1 step ~1900cyc >>
//    L2 latency): LDS = A 32K + mid 16K + 2x16K slots = 80KB exactly -> 2
//    independent 4-wave blocks/CU whose barrier groups drift out of phase.
//  - bU loaded global->regs per slice at end of step j1 (keeps the constant
//    vmcnt(4) bookkeeping exact; completes by j3's wait).
//  - everything else unchanged.

#define GG 2048
#define DD 256
#define NROWS 32768
#define NC 32
#define CS 64

typedef __attribute__((ext_vector_type(8))) short bf16x8;
typedef __attribute__((ext_vector_type(4))) float f32x4;

struct FalseT { static constexpr bool value = false; };
struct TrueT  { static constexpr bool value = true;  };

__device__ __forceinline__ short f2bf(float f) {
  union { float f; unsigned u; } v; v.f = f;
  unsigned r = v.u + 0x7FFFu + ((v.u >> 16) & 1u);
  return (short)(r >> 16);
}
__device__ __forceinline__ float bf2f(short s) {
  union { unsigned u; float f; } v; v.u = ((unsigned)(unsigned short)s) << 16;
  return v.f;
}
__device__ __forceinline__ void gld16(const short* g, short* l) {
  __builtin_amdgcn_global_load_lds(
      (const __attribute__((address_space(1))) void*)g,
      (__attribute__((address_space(3))) void*)l, 16, 0, 0);
}
__device__ __forceinline__ float fast_gelu(float x) {
  float y = 1.595769122f * (x + 0.044715f * x * x * x);
  return x / (1.0f + __expf(-y));
}

// ---------------- embed ------------------------------------------------------
__global__ __launch_bounds__(256) void embed_kernel(
    const float* __restrict__ x, const float* __restrict__ ge,
    const float* __restrict__ invf, float* __restrict__ h) {
  int bg = blockIdx.x * 4 + (threadIdx.x >> 6);
  int g = bg & (GG - 1);
  int lane = threadIdx.x & 63;
  float xv = x[bg];
  int d = lane * 4;
  float4 e;
  if (lane < 32) {
    float4 f = *(const float4*)&invf[d];
    e.x = sinf(xv * f.x); e.y = sinf(xv * f.y);
    e.z = sinf(xv * f.z); e.w = sinf(xv * f.w);
  } else {
    float4 f = *(const float4*)&invf[d - 128];
    e.x = cosf(xv * f.x); e.y = cosf(xv * f.y);
    e.z = cosf(xv * f.z); e.w = cosf(xv * f.w);
  }
  if (xv == -10.0f) { e.x = 0.f; e.y = 0.f; e.z = 0.f; e.w = 0.f; }
  float4 gv = *(const float4*)&ge[(size_t)g * DD + d];
  float4 o; o.x = gv.x + e.x; o.y = gv.y + e.y; o.z = gv.z + e.z; o.w = gv.w + e.w;
  *(float4*)&h[(size_t)bg * DD + d] = o;
}

// ---------------- layernorm -> TILED bf16 ------------------------------------
__global__ __launch_bounds__(256) void ln_tiled(
    const float* __restrict__ h, const float* __restrict__ gamma,
    const float* __restrict__ beta, short* __restrict__ outT) {
  __shared__ float mean_s[32], rstd_s[32];
  __shared__ float gls[256], bls[256];
  int r0 = blockIdx.x * 32;
  int tid = threadIdx.x;
  gls[tid] = gamma[tid]; bls[tid] = beta[tid];
  {
    int row = tid >> 3, seg = tid & 7;
    const float4* hp = (const float4*)(h + (size_t)(r0 + row) * DD + seg * 32);
    float s = 0.f, s2 = 0.f;
#pragma unroll
    for (int i = 0; i < 8; ++i) {
      float4 v = hp[i];
      s += v.x + v.y + v.z + v.w;
      s2 += v.x * v.x + v.y * v.y + v.z * v.z + v.w * v.w;
    }
    s += __shfl_xor(s, 1); s += __shfl_xor(s, 2); s += __shfl_xor(s, 4);
    s2 += __shfl_xor(s2, 1); s2 += __shfl_xor(s2, 2); s2 += __shfl_xor(s2, 4);
    if (seg == 0) {
      float mn = s * (1.0f / 256.0f);
      mean_s[row] = mn;
      rstd_s[row] = rsqrtf(s2 * (1.0f / 256.0f) - mn * mn + 1e-5f);
    }
  }
  __syncthreads();
  int row = tid & 31, kc8 = (tid >> 5) & 3, half = tid >> 7;
  float mn = mean_s[row], rs = rstd_s[row];
  size_t hrow = (size_t)(r0 + row) * DD;
  int trow = (r0 & 127) + row;
  short* tb = outT + (size_t)(r0 >> 7) * 8 * 4096 + (kc8 * 128 + trow) * 8;
#pragma unroll
  for (int j = 0; j < 4; ++j) {
    int kb = half * 4 + j;
    int k0 = kb * 32 + kc8 * 8;
    float4 x0 = *(const float4*)&h[hrow + k0];
    float4 x1 = *(const float4*)&h[hrow + k0 + 4];
    float4 g0 = *(const float4*)&gls[k0], g1 = *(const float4*)&gls[k0 + 4];
    float4 b0 = *(const float4*)&bls[k0], b1 = *(const float4*)&bls[k0 + 4];
    bf16x8 aw;
    aw[0] = f2bf((x0.x - mn) * rs * g0.x + b0.x);
    aw[1] = f2bf((x0.y - mn) * rs * g0.y + b0.y);
    aw[2] = f2bf((x0.z - mn) * rs * g0.z + b0.z);
    aw[3] = f2bf((x0.w - mn) * rs * g0.w + b0.w);
    aw[4] = f2bf((x1.x - mn) * rs * g1.x + b1.x);
    aw[5] = f2bf((x1.y - mn) * rs * g1.y + b1.y);
    aw[6] = f2bf((x1.z - mn) * rs * g1.z + b1.z);
    aw[7] = f2bf((x1.w - mn) * rs * g1.w + b1.w);
    *(bf16x8*)&tb[(size_t)kb * 4096] = aw;
  }
}

// ---------------- weight convert+transpose -> TILED --------------------------
__global__ __launch_bounds__(256) void prep_weights(
    const float* __restrict__ Wq, const float* __restrict__ Wk,
    const float* __restrict__ Wv, const float* __restrict__ WU,
    const float* __restrict__ WV,
    short* __restrict__ TQ, short* __restrict__ TK, short* __restrict__ TV,
    short* __restrict__ TU, short* __restrict__ TVd) {
  int zz = blockIdx.z, l = blockIdx.y;
  const float* src; short* dst; int Kd, Nd;
  if (zz == 0) { src = Wq; dst = TQ; Kd = 256; Nd = 256; }
  else if (zz == 1) { src = Wk; dst = TK; Kd = 256; Nd = 256; }
  else if (zz == 2) { src = Wv; dst = TV; Kd = 256; Nd = 256; }
  else if (zz == 3) { src = WU; dst = TU; Kd = 256; Nd = 1024; }
  else { src = WV; dst = TVd; Kd = 1024; Nd = 256; }
  int tot = Kd * Nd;
  int e = blockIdx.x * 256 + threadIdx.x;
  if (e >= tot) return;
  int t = e >> 12;
  int cslot = (e >> 3) & 511;
  int elem = e & 7;
  int kc8 = cslot >> 7, rn = cslot & 127;
  int nKb = Kd >> 5;
  int nt = t / nKb, kb = t - nt * nKb;
  int n = nt * 128 + rn, k = kb * 32 + kc8 * 8 + elem;
  dst[(size_t)l * tot + e] = f2bf(src[(size_t)l * tot + (size_t)k * Nd + n]);
}

// ---------------- bf16 MFMA GEMM (tiled operands, compile-time K) -------------
// 3-buffer rolling pipeline, fully unrolled. EPI 0: square(z<2), HEAD-MAJOR
// bf16 out via LDS transpose (QKV path).
template <int K, int EPI>
__global__ __launch_bounds__(256) void gemm_t(
    const short* __restrict__ A, const short* __restrict__ B0,
    const short* __restrict__ B1, const short* __restrict__ B2,
    const float* __restrict__ bias0, const float* __restrict__ bias1,
    const float* __restrict__ bias2,
    short* __restrict__ o0, short* __restrict__ o1, short* __restrict__ o2,
    float* __restrict__ outf, int N) {
  __shared__ __align__(16) short L[24576];  // 48KB: As g @ g*4096, Bs g @ 12288+g*4096
  constexpr int nIter = K / 32;
  int z = blockIdx.z;
  const short* Bt = (z == 0) ? B0 : (z == 1) ? B1 : B2;
  const float* bias = (z == 0) ? bias0 : (z == 1) ? bias1 : bias2;
  short* outz = (z == 0) ? o0 : (z == 1) ? o1 : o2;
  int m0 = blockIdx.x * 128, n0 = blockIdx.y * 128;
  int tid = threadIdx.x;
  int lane = tid & 63, w = tid >> 6;
  int q = lane >> 4, r = lane & 15;
  int wm = (w >> 1) * 64, wn = (w & 1) * 64;
  const short* At = A + (size_t)blockIdx.x * nIter * 4096;
  const short* Btl = Bt + (size_t)blockIdx.y * nIter * 4096;
  f32x4 vzero = {0.f, 0.f, 0.f, 0.f};
  f32x4 acc[4][4];
#pragma unroll
  for (int i = 0; i < 4; ++i)
#pragma unroll
    for (int j = 0; j < 4; ++j) acc[i][j] = vzero;

  int c0 = tid * 8, c1 = (tid + 256) * 8;
  // prologue: groups 0,1,2
#pragma unroll
  for (int g = 0; g < 3; ++g) {
    gld16(At + g * 4096 + c0, &L[g * 4096 + c0]);
    gld16(At + g * 4096 + c1, &L[g * 4096 + c1]);
    gld16(Btl + g * 4096 + c0, &L[12288 + g * 4096 + c0]);
    gld16(Btl + g * 4096 + c1, &L[12288 + g * 4096 + c1]);
  }

  int abase = (q * 128 + wm + r) * 8;
  int bbase = (q * 128 + wn + r) * 8;

#pragma unroll
  for (int gi = 0; gi < nIter; ++gi) {
    const int rem = nIter - 1 - gi;  // groups still needed after this one
    if (rem >= 2)      __builtin_amdgcn_s_waitcnt(0x0f78);  // vmcnt(8)
    else if (rem == 1) __builtin_amdgcn_s_waitcnt(0x0f74);  // vmcnt(4)
    else               __builtin_amdgcn_s_waitcnt(0x0f70);  // vmcnt(0)
    __builtin_amdgcn_s_barrier();
    const int cur = gi % 3;
    const short* Asc = &L[cur * 4096];
    const short* Bsc = &L[12288 + cur * 4096];
    bf16x8 af[4], bfr[4];
#pragma unroll
    for (int mt = 0; mt < 4; ++mt)
      af[mt] = *(const bf16x8*)&Asc[abase + mt * 16 * 8];
#pragma unroll
    for (int nt = 0; nt < 4; ++nt)
      bfr[nt] = *(const bf16x8*)&Bsc[bbase + nt * 16 * 8];
#pragma unroll
    for (int mt = 0; mt < 4; ++mt)
#pragma unroll
      for (int nt = 0; nt < 4; ++nt)
        acc[mt][nt] = __builtin_amdgcn_mfma_f32_16x16x32_bf16(bfr[nt], af[mt], acc[mt][nt], 0, 0, 0);
    __builtin_amdgcn_s_waitcnt(0xc07f);  // lgkmcnt(0)
    __builtin_amdgcn_s_barrier();
    if (gi + 3 < nIter) {
      size_t kn = (size_t)(gi + 3) * 4096;
      gld16(At + kn + c0, &L[cur * 4096 + c0]);
      gld16(At + kn + c1, &L[cur * 4096 + c1]);
      gld16(Btl + kn + c0, &L[12288 + cur * 4096 + c0]);
      gld16(Btl + kn + c1, &L[12288 + cur * 4096 + c1]);
    }
  }

  float4 bias4[4];
#pragma unroll
  for (int nt = 0; nt < 4; ++nt) bias4[nt] = *(const float4*)&bias[n0 + wn + nt * 16 + q * 4];

  if (EPI == 0) {
    // stage tile to LDS [128][132] (pad: 2-way-free banks), then write head-major
    short* T = L;
#pragma unroll
    for (int mt = 0; mt < 4; ++mt) {
      int ml = wm + mt * 16 + r;
#pragma unroll
      for (int nt = 0; nt < 4; ++nt) {
        f32x4 v = acc[mt][nt];
        v[0] += bias4[nt].x; v[1] += bias4[nt].y; v[2] += bias4[nt].z; v[3] += bias4[nt].w;
        if (z < 2) { v[0] *= v[0]; v[1] *= v[1]; v[2] *= v[2]; v[3] *= v[3]; }
        short4 pk; pk.x = f2bf(v[0]); pk.y = f2bf(v[1]); pk.z = f2bf(v[2]); pk.w = f2bf(v[3]);
        *(short4*)&T[ml * 132 + wn + nt * 16 + q * 4] = pk;
      }
    }
    __syncthreads();
#pragma unroll
    for (int t2 = 0; t2 < 2; ++t2) {
      int task = tid + t2 * 256;
      int row = task & 127, hl = task >> 7;
      size_t obase = ((size_t)((n0 >> 5) + hl) * NROWS + m0 + row) * 32;
#pragma unroll
      for (int j = 0; j < 4; ++j)
        *(bf16x8*)&outz[obase + j * 8] = *(const bf16x8*)&T[row * 132 + hl * 32 + j * 8];
    }
  } else if (EPI == 1) {
#pragma unroll
    for (int mt = 0; mt < 4; ++mt) {
      int ml = wm + mt * 16 + r;
#pragma unroll
      for (int nt = 0; nt < 4; ++nt) {
        f32x4 v = acc[mt][nt];
        v[0] += bias4[nt].x; v[1] += bias4[nt].y; v[2] += bias4[nt].z; v[3] += bias4[nt].w;
#pragma unroll
        for (int e = 0; e < 4; ++e) v[e] = fast_gelu(v[e]);
        short4 o; o.x = f2bf(v[0]); o.y = f2bf(v[1]); o.z = f2bf(v[2]); o.w = f2bf(v[3]);
        int n = n0 + wn + nt * 16 + q * 4;
        size_t ti = ((size_t)blockIdx.x * (N >> 5) + (n >> 5)) * 4096 +
                    (size_t)(((n >> 3) & 3) << 10) + (ml << 3) + (n & 7);
        *(short4*)&outz[ti] = o;
      }
    }
  } else {
    // h += acc + bias, staged via LDS [128][68] f32, two 64-n rounds
    float* TF = (float*)L;
#pragma unroll
    for (int half = 0; half < 2; ++half) {
      __syncthreads();
      if ((w & 1) == half) {
#pragma unroll
        for (int mt = 0; mt < 4; ++mt) {
          int ml = wm + mt * 16 + r;
#pragma unroll
          for (int nt = 0; nt < 4; ++nt) {
            f32x4 v = acc[mt][nt];
            v[0] += bias4[nt].x; v[1] += bias4[nt].y; v[2] += bias4[nt].z; v[3] += bias4[nt].w;
            *(f32x4*)&TF[ml * 68 + nt * 16 + q * 4] = v;
          }
        }
      }
      __syncthreads();
      int row = tid >> 1, col = (tid & 1) * 32;
      size_t hoff = (size_t)(m0 + row) * N + n0 + half * 64 + col;
#pragma unroll
      for (int j = 0; j < 8; ++j) {
        float4 add = *(const float4*)&TF[row * 68 + col + j * 4];
        float4 cur4 = *(float4*)&outf[hoff + j * 4];
        cur4.x += add.x; cur4.y += add.y; cur4.z += add.z; cur4.w += add.w;
        *(float4*)&outf[hoff + j * 4] = cur4;
      }
    }
  }
}

// ---------------- fused FFN: h += gelu(hn@WU+bU)@WV + bV ---------------------
// 512 blocks x 256 threads (2 blocks/CU via 80KB LDS), 64 rows/block, 4 waves.
// A strip in LDS (32KB, compact 64-row tiled layout), fragments re-read per
// step (R12-proven spill-free profile: persistent regs = accm32+acco64 only).
// 2-slot weight pipeline (weights L2-hot; 1-step slack covers L2 latency):
// steps sig=0..63 (8 slices x {4 up + 4 down}), slot(sig) in buf[sig&1],
// issue slot(sig+2) at end of step sig, constant vmcnt(4); final step vmcnt(0).
// bU loaded global->regs at end of step j==1 per slice (keeps counts exact).
// LDS (shorts): A[0,16384) mid[16384,24576) buf0[24576,32768) buf1[32768,40960).
__global__ __launch_bounds__(256) void ffn_fused(
    const short* __restrict__ A, const short* __restrict__ TUw,
    const short* __restrict__ TVw, const float* __restrict__ bUp,
    const float* __restrict__ bVp, float* __restrict__ h) {
  __shared__ __align__(16) short L[40960];  // 80KB
  int tid = threadIdx.x;
  int lane = tid & 63, w = tid >> 6;
  int q = lane >> 4, r = lane & 15;
  int wmU = (w >> 1) * 32, wnU = (w & 1) * 64;   // up: wave = 32 rows x 64 f
  int wmD = (w >> 1) * 32, wnD = (w & 1) * 128;  // down: wave = 32 rows x 128 d
  const short* At = A + (size_t)(blockIdx.x >> 1) * 32768;  // 128-row tile
  int rbase = (blockIdx.x & 1) * 64;                        // 64-row half

  // A -> LDS (oldest vmem): per kb, compact 64-row layout [kb][kc8*64+row][8]
  {
    int chunk = tid >> 6, rr2 = tid & 63;
#pragma unroll
    for (int kb = 0; kb < 8; ++kb)
      gld16(At + kb * 4096 + (chunk * 128 + rbase + rr2) * 8,
            &L[kb * 2048 + tid * 8]);
  }

  auto issueFor = [&](int t) {  // stage slot(t) into buf[t&1]
    short* dst = &L[24576 + (t & 1) * 8192];
    int ss = t >> 3, pp = t & 7;
    if (pp < 4) {  // up weights: WU tiles (ss*8+pp*2, +1)
      const short* g0 = TUw + ((size_t)ss * 8 + pp * 2) * 4096;
#pragma unroll
      for (int i = 0; i < 4; ++i)
        gld16(g0 + (i * 256 + tid) * 8, dst + (i * 256 + tid) * 8);
    } else {       // down weights: WV tiles (kbg, 32+kbg), kbg=ss*4+pp-4
      int kbg = ss * 4 + pp - 4;
      const short* gA = TVw + (size_t)kbg * 4096;
      const short* gB = TVw + (size_t)(32 + kbg) * 4096;
#pragma unroll
      for (int i = 0; i < 2; ++i) {
        gld16(gA + (i * 256 + tid) * 8, dst + (i * 256 + tid) * 8);
        gld16(gB + (i * 256 + tid) * 8, dst + 4096 + (i * 256 + tid) * 8);
      }
    }
  };

  issueFor(0); issueFor(1);

  f32x4 vzero = {0.f, 0.f, 0.f, 0.f};
  f32x4 accm[2][4], acco[2][8];
#pragma unroll
  for (int mt = 0; mt < 2; ++mt) {
#pragma unroll
    for (int nt = 0; nt < 4; ++nt) accm[mt][nt] = vzero;
#pragma unroll
    for (int nt = 0; nt < 8; ++nt) acco[mt][nt] = vzero;
  }
  float4 b4[4];

  auto slice = [&](int s, auto lastc) {
    constexpr bool LAST = decltype(lastc)::value;
    // ---- up steps j=0..3: slot(s*8+j) holds WU kb = 2j,2j+1 ----
#pragma unroll
    for (int j = 0; j < 4; ++j) {
      int sig = s * 8 + j;
      __builtin_amdgcn_s_waitcnt(0x0f74);  // vmcnt(4)
      __builtin_amdgcn_s_barrier();
      const short* Ws = &L[24576 + (sig & 1) * 8192];
#pragma unroll
      for (int kk = 0; kk < 2; ++kk) {
        int kb = j * 2 + kk;
        bf16x8 af[2], bfr[4];
#pragma unroll
        for (int mt = 0; mt < 2; ++mt)
          af[mt] = *(const bf16x8*)&L[kb * 2048 + (q * 64 + wmU + mt * 16 + r) * 8];
#pragma unroll
        for (int nt = 0; nt < 4; ++nt)
          bfr[nt] = *(const bf16x8*)&Ws[kk * 4096 + (q * 128 + wnU + nt * 16 + r) * 8];
#pragma unroll
        for (int mt = 0; mt < 2; ++mt)
#pragma unroll
          for (int nt = 0; nt < 4; ++nt)
            accm[mt][nt] = __builtin_amdgcn_mfma_f32_16x16x32_bf16(
                bfr[nt], af[mt], accm[mt][nt], 0, 0, 0);
      }
      if (j == 3) {  // slice's K done: bias + gelu + pack -> mid (64-row A-tile)
#pragma unroll
        for (int mt = 0; mt < 2; ++mt) {
          int row = wmU + mt * 16 + r;
#pragma unroll
          for (int nt = 0; nt < 4; ++nt) {
            f32x4 v = accm[mt][nt];
            v[0] += b4[nt].x; v[1] += b4[nt].y; v[2] += b4[nt].z; v[3] += b4[nt].w;
            short4 pk;
            pk.x = f2bf(fast_gelu(v[0])); pk.y = f2bf(fast_gelu(v[1]));
            pk.z = f2bf(fast_gelu(v[2])); pk.w = f2bf(fast_gelu(v[3]));
            int f0 = wnU + nt * 16 + q * 4;
            *(short4*)&L[16384 + (f0 >> 5) * 2048 + (((f0 >> 3) & 3) * 64 + row) * 8 + (f0 & 7)] = pk;
            accm[mt][nt] = vzero;
          }
        }
      }
      __builtin_amdgcn_s_waitcnt(0xc07f);  // lgkmcnt(0)
      __builtin_amdgcn_s_barrier();
      issueFor(sig + 2);  // sig<=59 here when issued; always valid (sig+2<=61? j<=3,s<=7 -> max 59+2=61<64)
      if (j == 1) {  // bU for this slice: youngest vmem, done by j3's vmcnt(4)
#pragma unroll
        for (int nt = 0; nt < 4; ++nt)
          b4[nt] = *(const float4*)&bUp[s * 128 + wnU + nt * 16 + q * 4];
      }
    }
    // ---- down steps i=0..3: mid kb'=i, slot(s*8+4+i) = WV kbg=s*4+i ----
#pragma unroll
    for (int i = 0; i < 4; ++i) {
      int sig = s * 8 + 4 + i;
      if (LAST && i == 3) __builtin_amdgcn_s_waitcnt(0x0f70);  // vmcnt(0)
      else                __builtin_amdgcn_s_waitcnt(0x0f74);  // vmcnt(4)
      __builtin_amdgcn_s_barrier();
      const short* Ws = &L[24576 + (sig & 1) * 8192];
      bf16x8 am[2], bvf[8];
#pragma unroll
      for (int mt = 0; mt < 2; ++mt)
        am[mt] = *(const bf16x8*)&L[16384 + i * 2048 + (q * 64 + wmD + mt * 16 + r) * 8];
#pragma unroll
      for (int nt = 0; nt < 8; ++nt)
        bvf[nt] = *(const bf16x8*)&Ws[(wnD >> 7) * 4096 + (q * 128 + (wnD & 127) + nt * 16 + r) * 8];
#pragma unroll
      for (int mt = 0; mt < 2; ++mt)
#pragma unroll
        for (int nt = 0; nt < 8; ++nt)
          acco[mt][nt] = __builtin_amdgcn_mfma_f32_16x16x32_bf16(bvf[nt], am[mt], acco[mt][nt], 0, 0, 0);
      __builtin_amdgcn_s_waitcnt(0xc07f);  // lgkmcnt(0)
      __builtin_amdgcn_s_barrier();
      if (!LAST || i < 2) issueFor(sig + 2);
    }
  };

  for (int s = 0; s < 7; ++s) slice(s, FalseT{});
  slice(7, TrueT{});

  // epilogue: out += bV; stage [64][260] f32 in LDS; coalesced h RMW
  float4 bv4[8];
#pragma unroll
  for (int nt = 0; nt < 8; ++nt) bv4[nt] = *(const float4*)&bVp[wnD + nt * 16 + q * 4];
  float* TF = (float*)L;
#pragma unroll
  for (int mt = 0; mt < 2; ++mt) {
    int row = wmD + mt * 16 + r;
#pragma unroll
    for (int nt = 0; nt < 8; ++nt) {
      f32x4 v = acco[mt][nt];
      v[0] += bv4[nt].x; v[1] += bv4[nt].y; v[2] += bv4[nt].z; v[3] += bv4[nt].w;
      *(f32x4*)&TF[row * 260 + wnD + nt * 16 + q * 4] = v;
    }
  }
  __syncthreads();
  int row2 = tid >> 2, col2 = (tid & 3) * 64;
  size_t hbase = ((size_t)blockIdx.x * 64 + row2) * DD + col2;
#pragma unroll
  for (int j = 0; j < 16; ++j) {
    float4 add = *(const float4*)&TF[row2 * 260 + col2 + j * 4];
    float4 c4 = *(float4*)&h[hbase + j * 4];
    c4.x += add.x; c4.y += add.y; c4.z += add.z; c4.w += add.w;
    *(float4*)&h[hbase + j * 4] = c4;
  }
}

// ---------------- attention A1: per (b,h,chunk) S_c = K^T V, z_c = sum k ------
// q/k/v head-major: [head][32768][32]
__global__ __launch_bounds__(256) void attn_chunk_kv(
    const short* __restrict__ Kb, const short* __restrict__ Vb,
    float* __restrict__ St, float* __restrict__ Zc) {
  __shared__ short Kt[4][32 * 72];
  __shared__ short Vt[4][32 * 72];
  int wid = threadIdx.x >> 6;
  int blk = blockIdx.x * 4 + wid;
  int c = blk & (NC - 1), bh = blk >> 5;
  int b = bh >> 3, hh = bh & 7;
  int lane = threadIdx.x & 63, q = lane >> 4, r = lane & 15;
  size_t rowbase = ((size_t)hh * NROWS + b * GG + c * CS + lane) * 32;
#pragma unroll
  for (int j = 0; j < 4; ++j) {
    bf16x8 kv = *(const bf16x8*)&Kb[rowbase + j * 8];
    bf16x8 vv = *(const bf16x8*)&Vb[rowbase + j * 8];
#pragma unroll
    for (int e = 0; e < 8; ++e) {
      Kt[wid][(j * 8 + e) * 72 + lane] = kv[e];
      Vt[wid][(j * 8 + e) * 72 + lane] = vv[e];
    }
  }
  __syncthreads();
  f32x4 vzero = {0.f, 0.f, 0.f, 0.f};
  f32x4 acc[2][2];
#pragma unroll
  for (int i = 0; i < 2; ++i)
#pragma unroll
    for (int j = 0; j < 2; ++j) acc[i][j] = vzero;
#pragma unroll
  for (int ks = 0; ks < 2; ++ks) {
    bf16x8 afr[2], bfr[2];
#pragma unroll
    for (int mt = 0; mt < 2; ++mt) afr[mt] = *(const bf16x8*)&Kt[wid][(mt * 16 + r) * 72 + ks * 32 + q * 8];
#pragma unroll
    for (int nt = 0; nt < 2; ++nt) bfr[nt] = *(const bf16x8*)&Vt[wid][(nt * 16 + r) * 72 + ks * 32 + q * 8];
#pragma unroll
    for (int mt = 0; mt < 2; ++mt)
#pragma unroll
      for (int nt = 0; nt < 2; ++nt)
        acc[mt][nt] = __builtin_amdgcn_mfma_f32_16x16x32_bf16(afr[mt], bfr[nt], acc[mt][nt], 0, 0, 0);
  }
  float* stp = St + ((size_t)bh * NC + c) * 1024;
#pragma unroll
  for (int mt = 0; mt < 2; ++mt)
#pragma unroll
    for (int nt = 0; nt < 2; ++nt)
      *(f32x4*)&stp[(nt * 16 + r) * 32 + mt * 16 + q * 4] = acc[mt][nt];  // St[d][f]
  if (lane < 32) {
    float s = 0.f;
#pragma unroll
    for (int j = 0; j < 8; ++j) {
      bf16x8 kr = *(const bf16x8*)&Kt[wid][lane * 72 + j * 8];
#pragma unroll
      for (int e = 0; e < 8; ++e) s += bf2f(kr[e]);
    }
    Zc[((size_t)bh * NC + c) * 32 + lane] = s;
  }
}

// ---------------- attention A2: exclusive prefix over chunks ------------------
__global__ __launch_bounds__(1024) void attn_prefix(float* __restrict__ St, float* __restrict__ Zc) {
  int bh = blockIdx.x, i = threadIdx.x;
  float run = 0.f;
  float* p = St + (size_t)bh * NC * 1024 + i;
#pragma unroll
  for (int c = 0; c < NC; ++c) { float t = p[(size_t)c * 1024]; p[(size_t)c * 1024] = run; run += t; }
  if (i < 32) {
    float rz = 0.f;
    float* pz = Zc + (size_t)bh * NC * 32 + i;
#pragma unroll
    for (int c = 0; c < NC; ++c) { float t = pz[c * 32]; pz[c * 32] = rz; rz += t; }
  }
}

// ---------------- attention B: intra-chunk + apply, h += out ------------------
__global__ __launch_bounds__(256) void attn_intra(
    const short* __restrict__ Qb, const short* __restrict__ Kb,
    const short* __restrict__ Vb, const float* __restrict__ St,
    const float* __restrict__ Zc, float* __restrict__ h) {
  __shared__ short P[4][64 * 72];
  __shared__ short Vt[4][32 * 72];
  __shared__ float den[4][64];
  int wid = threadIdx.x >> 6;
  int blk = blockIdx.x * 4 + wid;
  int c = blk & (NC - 1), bh = blk >> 5;
  int b = bh >> 3, hh = bh & 7;
  int lane = threadIdx.x & 63, q = lane >> 4, r = lane & 15;
  size_t hrow0 = (size_t)b * GG + c * CS;                 // rows in h (row-major)
  size_t qrow0 = (size_t)hh * NROWS + b * GG + c * CS;    // rows in head-major qkv

  const float* zp = Zc + ((size_t)bh * NC + c) * 32;
  float qz = 0.f;
  {
    size_t qoff = (qrow0 + lane) * 32;
#pragma unroll
    for (int j = 0; j < 4; ++j) {
      bf16x8 qv = *(const bf16x8*)&Qb[qoff + j * 8];
#pragma unroll
      for (int e = 0; e < 8; ++e) qz += bf2f(qv[e]) * zp[j * 8 + e];
    }
  }
  den[wid][lane] = qz;

  {
    size_t voff = (qrow0 + lane) * 32;
#pragma unroll
    for (int j = 0; j < 4; ++j) {
      bf16x8 vv = *(const bf16x8*)&Vb[voff + j * 8];
#pragma unroll
      for (int e = 0; e < 8; ++e) Vt[wid][(j * 8 + e) * 72 + lane] = vv[e];
    }
  }

  bf16x8 ak[4], bqf[4];
#pragma unroll
  for (int t4 = 0; t4 < 4; ++t4) {
    ak[t4]  = *(const bf16x8*)&Kb[(qrow0 + t4 * 16 + r) * 32 + q * 8];
    bqf[t4] = *(const bf16x8*)&Qb[(qrow0 + t4 * 16 + r) * 32 + q * 8];
  }
  f32x4 vzero = {0.f, 0.f, 0.f, 0.f};
  f32x4 pacc[4][4];
#pragma unroll
  for (int mt = 0; mt < 4; ++mt)
#pragma unroll
    for (int nt = 0; nt < 4; ++nt)
      pacc[mt][nt] = __builtin_amdgcn_mfma_f32_16x16x32_bf16(ak[mt], bqf[nt], vzero, 0, 0, 0);

  float rs[4] = {0.f, 0.f, 0.f, 0.f};
#pragma unroll
  for (int nt = 0; nt < 4; ++nt) {
    int t = nt * 16 + r;
#pragma unroll
    for (int mt = 0; mt < 4; ++mt) {
      short4 pk;
#pragma unroll
      for (int rr = 0; rr < 4; ++rr) {
        int s = mt * 16 + q * 4 + rr;
        float pv = (s <= t) ? pacc[mt][nt][rr] : 0.f;
        rs[nt] += pv;
        ((short*)&pk)[rr] = f2bf(pv);
      }
      *(short4*)&P[wid][t * 72 + mt * 16 + q * 4] = pk;
    }
  }
#pragma unroll
  for (int nt = 0; nt < 4; ++nt) {
    rs[nt] += __shfl_xor(rs[nt], 16);
    rs[nt] += __shfl_xor(rs[nt], 32);
  }
  __syncthreads();
  if (lane < 16) {
#pragma unroll
    for (int nt = 0; nt < 4; ++nt) den[wid][nt * 16 + lane] += rs[nt];
  }
  __syncthreads();

  f32x4 oacc[4][2];
#pragma unroll
  for (int mt = 0; mt < 4; ++mt)
#pragma unroll
    for (int nt2 = 0; nt2 < 2; ++nt2) oacc[mt][nt2] = vzero;
  const float* stp = St + ((size_t)bh * NC + c) * 1024;
#pragma unroll
  for (int nt2 = 0; nt2 < 2; ++nt2) {
    float4 s0 = *(const float4*)&stp[(nt2 * 16 + r) * 32 + q * 8];
    float4 s1 = *(const float4*)&stp[(nt2 * 16 + r) * 32 + q * 8 + 4];
    bf16x8 bs;
    bs[0] = f2bf(s0.x); bs[1] = f2bf(s0.y); bs[2] = f2bf(s0.z); bs[3] = f2bf(s0.w);
    bs[4] = f2bf(s1.x); bs[5] = f2bf(s1.y); bs[6] = f2bf(s1.z); bs[7] = f2bf(s1.w);
#pragma unroll
    for (int mt = 0; mt < 4; ++mt)
      oacc[mt][nt2] = __builtin_amdgcn_mfma_f32_16x16x32_bf16(bqf[mt], bs, oacc[mt][nt2], 0, 0, 0);
  }
#pragma unroll
  for (int ks = 0; ks < 2; ++ks) {
    bf16x8 ap[4];
#pragma unroll
    for (int mt = 0; mt < 4; ++mt)
      ap[mt] = *(const bf16x8*)&P[wid][(mt * 16 + r) * 72 + ks * 32 + q * 8];
#pragma unroll
    for (int nt2 = 0; nt2 < 2; ++nt2) {
      bf16x8 bv_ = *(const bf16x8*)&Vt[wid][(nt2 * 16 + r) * 72 + ks * 32 + q * 8];
#pragma unroll
      for (int mt = 0; mt < 4; ++mt)
        oacc[mt][nt2] = __builtin_amdgcn_mfma_f32_16x16x32_bf16(ap[mt], bv_, oacc[mt][nt2], 0, 0, 0);
    }
  }

#pragma unroll
  for (int mt = 0; mt < 4; ++mt) {
#pragma unroll
    for (int rr = 0; rr < 4; ++rr) {
      int t = mt * 16 + q * 4 + rr;
      float inv = 1.0f / (den[wid][t] + 1e-16f);
#pragma unroll
      for (int nt2 = 0; nt2 < 2; ++nt2) {
        int d = nt2 * 16 + r;
        size_t off = (hrow0 + t) * DD + hh * 32 + d;
        h[off] += oacc[mt][nt2][rr] * inv;
      }
    }
  }
}

// ---------------- final projection -------------------------------------------
__global__ __launch_bounds__(256) void out_proj(
    const float* __restrict__ h, const float* __restrict__ Wout,
    const float* __restrict__ bout, float* __restrict__ out) {
  int row = blockIdx.x * 4 + (threadIdx.x >> 6);
  int lane = threadIdx.x & 63;
  float4 a = *(const float4*)&h[(size_t)row * DD + lane * 4];
  float4 w = *(const float4*)&Wout[lane * 4];
  float s = a.x * w.x + a.y * w.y + a.z * w.z + a.w * w.w;
#pragma unroll
  for (int o = 1; o < 64; o <<= 1) s += __shfl_xor(s, o);
  if (lane == 0) out[row] = s + bout[0];
}

extern "C" void kernel_launch(void* const* d_in, const int* in_sizes, int n_in,
                              void* d_out, int out_size, void* d_ws, size_t ws_size,
                              hipStream_t stream) {
  const float* x    = (const float*)d_in[0];
  const float* ge   = (const float*)d_in[1];
  const float* invf = (const float*)d_in[2];
  const float* Wq   = (const float*)d_in[3];
  const float* bq   = (const float*)d_in[4];
  const float* Wk   = (const float*)d_in[5];
  const float* bk   = (const float*)d_in[6];
  const float* Wv   = (const float*)d_in[7];
  const float* bv   = (const float*)d_in[8];
  const float* ln1g = (const float*)d_in[9];
  const float* ln1b = (const float*)d_in[10];
  const float* ln2g = (const float*)d_in[11];
  const float* ln2b = (const float*)d_in[12];
  const float* WU   = (const float*)d_in[13];
  const float* bU   = (const float*)d_in[14];
  const float* WV   = (const float*)d_in[15];
  const float* bV   = (const float*)d_in[16];
  const float* Wout = (const float*)d_in[17];
  const float* bout = (const float*)d_in[18];
  float* out = (float*)d_out;

  char* ws = (char*)d_ws;
  float* h   = (float*)(ws + 0);            // 33.5 MB
  short* hn  = (short*)(ws + 33554432);     // 16.8 MB (tiled)
  char*  R   = ws + 50331648;               // shared region
  short* qb  = (short*)(R + 0);             // head-major [8][32768][32]
  short* kb  = (short*)(R + 16777216);
  short* vb  = (short*)(R + 33554432);
  float* St  = (float*)(R + 50331648);
  float* Zc  = (float*)(R + 67108864);
  char*  WT  = R + 67633152;
  short* TQ  = (short*)(WT + 0);
  short* TK  = (short*)(WT + 524288);
  short* TVq = (short*)(WT + 1048576);
  short* TU  = (short*)(WT + 1572864);
  short* TVd = (short*)(WT + 3670016);

  prep_weights<<<dim3(1024, 4, 5), 256, 0, stream>>>(Wq, Wk, Wv, WU, WV, TQ, TK, TVq, TU, TVd);
  embed_kernel<<<NROWS / 4, 256, 0, stream>>>(x, ge, invf, h);

  for (int l = 0; l < 4; ++l) {
    ln_tiled<<<NROWS / 32, 256, 0, stream>>>(h, ln1g + l * 256, ln1b + l * 256, hn);
    gemm_t<256, 0><<<dim3(256, 2, 3), 256, 0, stream>>>(
        hn, TQ + l * 65536, TK + l * 65536, TVq + l * 65536,
        bq + l * 256, bk + l * 256, bv + l * 256,
        qb, kb, vb, nullptr, 256);
    attn_chunk_kv<<<1024, 256, 0, stream>>>(kb, vb, St, Zc);
    attn_prefix<<<128, 1024, 0, stream>>>(St, Zc);
    attn_intra<<<1024, 256, 0, stream>>>(qb, kb, vb, St, Zc, h);
    ln_tiled<<<NROWS / 32, 256, 0, stream>>>(h, ln2g + l * 256, ln2b + l * 256, hn);
    ffn_fused<<<512, 256, 0, stream>>>(hn, TU + l * 262144, TVd + l * 262144,
                                       bU + l * 1024, bV + l * 256, h);
  }
  out_proj<<<NROWS / 4, 256, 0, stream>>>(h, Wout, bout, out);
}

// Round 8
// 756.412 us; speedup vs baseline: 1.0412x; 1.0412x over previous
//
#include <hip/hip_runtime.h>
#include <math.h>

// ExpressionPerformer: B=16,G=2048,D=256,H=8,dh=32,FFN=1024,L=4
// Round-17: revert ffn_fused to the PROVEN R11 structure (1 block/CU, 512 thr,
// A+mid in LDS, clean 32.7MB writes, 66us) and HALVE the step count:
//  - 32 slot-steps (was 64) with 32KB slots, 2-slot double buffer.
//    Per-step overhead (~1500cyc barrier/waitcnt skew, shared by all waves in
//    the single barrier group) is per-STEP, not per-byte -> halving steps
//    should cut ~16us.
//  - LDS = A 64K + mid 32K + 2x32K slots = 160KB exactly (gfx950 max).
//    bU -> registers (b4[2]/wave), loaded BEFORE the slot-issue at end of
//    up-step p0 so the uniform vmcnt(4) drains them with the older slot.
//  - Uniform 4 gld16/thread per slot -> constant vmcnt(4); final steps 4/0.
//  - Epilogue = R11 full-row writes (R13-16's 16B-granule epilogue caused the
//    4x write amplification: 137MB vs 33.5MB).
//  - 2-blocks/CU phase-drift arc (R13-16) abandoned: never beat R11.

#define GG 2048
#define DD 256
#define NROWS 32768
#define NC 32
#define CS 64

typedef __attribute__((ext_vector_type(8))) short bf16x8;
typedef __attribute__((ext_vector_type(4))) float f32x4;

struct FalseT { static constexpr bool value = false; };
struct TrueT  { static constexpr bool value = true;  };

__device__ __forceinline__ short f2bf(float f) {
  union { float f; unsigned u; } v; v.f = f;
  unsigned r = v.u + 0x7FFFu + ((v.u >> 16) & 1u);
  return (short)(r >> 16);
}
__device__ __forceinline__ float bf2f(short s) {
  union { unsigned u; float f; } v; v.u = ((unsigned)(unsigned short)s) << 16;
  return v.f;
}
__device__ __forceinline__ void gld16(const short* g, short* l) {
  __builtin_amdgcn_global_load_lds(
      (const __attribute__((address_space(1))) void*)g,
      (__attribute__((address_space(3))) void*)l, 16, 0, 0);
}
__device__ __forceinline__ float fast_gelu(float x) {
  float y = 1.595769122f * (x + 0.044715f * x * x * x);
  return x / (1.0f + __expf(-y));
}

// ---------------- embed ------------------------------------------------------
__global__ __launch_bounds__(256) void embed_kernel(
    const float* __restrict__ x, const float* __restrict__ ge,
    const float* __restrict__ invf, float* __restrict__ h) {
  int bg = blockIdx.x * 4 + (threadIdx.x >> 6);
  int g = bg & (GG - 1);
  int lane = threadIdx.x & 63;
  float xv = x[bg];
  int d = lane * 4;
  float4 e;
  if (lane < 32) {
    float4 f = *(const float4*)&invf[d];
    e.x = sinf(xv * f.x); e.y = sinf(xv * f.y);
    e.z = sinf(xv * f.z); e.w = sinf(xv * f.w);
  } else {
    float4 f = *(const float4*)&invf[d - 128];
    e.x = cosf(xv * f.x); e.y = cosf(xv * f.y);
    e.z = cosf(xv * f.z); e.w = cosf(xv * f.w);
  }
  if (xv == -10.0f) { e.x = 0.f; e.y = 0.f; e.z = 0.f; e.w = 0.f; }
  float4 gv = *(const float4*)&ge[(size_t)g * DD + d];
  float4 o; o.x = gv.x + e.x; o.y = gv.y + e.y; o.z = gv.z + e.z; o.w = gv.w + e.w;
  *(float4*)&h[(size_t)bg * DD + d] = o;
}

// ---------------- layernorm -> TILED bf16 ------------------------------------
__global__ __launch_bounds__(256) void ln_tiled(
    const float* __restrict__ h, const float* __restrict__ gamma,
    const float* __restrict__ beta, short* __restrict__ outT) {
  __shared__ float mean_s[32], rstd_s[32];
  __shared__ float gls[256], bls[256];
  int r0 = blockIdx.x * 32;
  int tid = threadIdx.x;
  gls[tid] = gamma[tid]; bls[tid] = beta[tid];
  {
    int row = tid >> 3, seg = tid & 7;
    const float4* hp = (const float4*)(h + (size_t)(r0 + row) * DD + seg * 32);
    float s = 0.f, s2 = 0.f;
#pragma unroll
    for (int i = 0; i < 8; ++i) {
      float4 v = hp[i];
      s += v.x + v.y + v.z + v.w;
      s2 += v.x * v.x + v.y * v.y + v.z * v.z + v.w * v.w;
    }
    s += __shfl_xor(s, 1); s += __shfl_xor(s, 2); s += __shfl_xor(s, 4);
    s2 += __shfl_xor(s2, 1); s2 += __shfl_xor(s2, 2); s2 += __shfl_xor(s2, 4);
    if (seg == 0) {
      float mn = s * (1.0f / 256.0f);
      mean_s[row] = mn;
      rstd_s[row] = rsqrtf(s2 * (1.0f / 256.0f) - mn * mn + 1e-5f);
    }
  }
  __syncthreads();
  int row = tid & 31, kc8 = (tid >> 5) & 3, half = tid >> 7;
  float mn = mean_s[row], rs = rstd_s[row];
  size_t hrow = (size_t)(r0 + row) * DD;
  int trow = (r0 & 127) + row;
  short* tb = outT + (size_t)(r0 >> 7) * 8 * 4096 + (kc8 * 128 + trow) * 8;
#pragma unroll
  for (int j = 0; j < 4; ++j) {
    int kb = half * 4 + j;
    int k0 = kb * 32 + kc8 * 8;
    float4 x0 = *(const float4*)&h[hrow + k0];
    float4 x1 = *(const float4*)&h[hrow + k0 + 4];
    float4 g0 = *(const float4*)&gls[k0], g1 = *(const float4*)&gls[k0 + 4];
    float4 b0 = *(const float4*)&bls[k0], b1 = *(const float4*)&bls[k0 + 4];
    bf16x8 aw;
    aw[0] = f2bf((x0.x - mn) * rs * g0.x + b0.x);
    aw[1] = f2bf((x0.y - mn) * rs * g0.y + b0.y);
    aw[2] = f2bf((x0.z - mn) * rs * g0.z + b0.z);
    aw[3] = f2bf((x0.w - mn) * rs * g0.w + b0.w);
    aw[4] = f2bf((x1.x - mn) * rs * g1.x + b1.x);
    aw[5] = f2bf((x1.y - mn) * rs * g1.y + b1.y);
    aw[6] = f2bf((x1.z - mn) * rs * g1.z + b1.z);
    aw[7] = f2bf((x1.w - mn) * rs * g1.w + b1.w);
    *(bf16x8*)&tb[(size_t)kb * 4096] = aw;
  }
}

// ---------------- weight convert+transpose -> TILED --------------------------
__global__ __launch_bounds__(256) void prep_weights(
    const float* __restrict__ Wq, const float* __restrict__ Wk,
    const float* __restrict__ Wv, const float* __restrict__ WU,
    const float* __restrict__ WV,
    short* __restrict__ TQ, short* __restrict__ TK, short* __restrict__ TV,
    short* __restrict__ TU, short* __restrict__ TVd) {
  int zz = blockIdx.z, l = blockIdx.y;
  const float* src; short* dst; int Kd, Nd;
  if (zz == 0) { src = Wq; dst = TQ; Kd = 256; Nd = 256; }
  else if (zz == 1) { src = Wk; dst = TK; Kd = 256; Nd = 256; }
  else if (zz == 2) { src = Wv; dst = TV; Kd = 256; Nd = 256; }
  else if (zz == 3) { src = WU; dst = TU; Kd = 256; Nd = 1024; }
  else { src = WV; dst = TVd; Kd = 1024; Nd = 256; }
  int tot = Kd * Nd;
  int e = blockIdx.x * 256 + threadIdx.x;
  if (e >= tot) return;
  int t = e >> 12;
  int cslot = (e >> 3) & 511;
  int elem = e & 7;
  int kc8 = cslot >> 7, rn = cslot & 127;
  int nKb = Kd >> 5;
  int nt = t / nKb, kb = t - nt * nKb;
  int n = nt * 128 + rn, k = kb * 32 + kc8 * 8 + elem;
  dst[(size_t)l * tot + e] = f2bf(src[(size_t)l * tot + (size_t)k * Nd + n]);
}

// ---------------- bf16 MFMA GEMM (tiled operands, compile-time K) -------------
// 3-buffer rolling pipeline, fully unrolled. EPI 0: square(z<2), HEAD-MAJOR
// bf16 out via LDS transpose (QKV path).
template <int K, int EPI>
__global__ __launch_bounds__(256) void gemm_t(
    const short* __restrict__ A, const short* __restrict__ B0,
    const short* __restrict__ B1, const short* __restrict__ B2,
    const float* __restrict__ bias0, const float* __restrict__ bias1,
    const float* __restrict__ bias2,
    short* __restrict__ o0, short* __restrict__ o1, short* __restrict__ o2,
    float* __restrict__ outf, int N) {
  __shared__ __align__(16) short L[24576];  // 48KB: As g @ g*4096, Bs g @ 12288+g*4096
  constexpr int nIter = K / 32;
  int z = blockIdx.z;
  const short* Bt = (z == 0) ? B0 : (z == 1) ? B1 : B2;
  const float* bias = (z == 0) ? bias0 : (z == 1) ? bias1 : bias2;
  short* outz = (z == 0) ? o0 : (z == 1) ? o1 : o2;
  int m0 = blockIdx.x * 128, n0 = blockIdx.y * 128;
  int tid = threadIdx.x;
  int lane = tid & 63, w = tid >> 6;
  int q = lane >> 4, r = lane & 15;
  int wm = (w >> 1) * 64, wn = (w & 1) * 64;
  const short* At = A + (size_t)blockIdx.x * nIter * 4096;
  const short* Btl = Bt + (size_t)blockIdx.y * nIter * 4096;
  f32x4 vzero = {0.f, 0.f, 0.f, 0.f};
  f32x4 acc[4][4];
#pragma unroll
  for (int i = 0; i < 4; ++i)
#pragma unroll
    for (int j = 0; j < 4; ++j) acc[i][j] = vzero;

  int c0 = tid * 8, c1 = (tid + 256) * 8;
  // prologue: groups 0,1,2
#pragma unroll
  for (int g = 0; g < 3; ++g) {
    gld16(At + g * 4096 + c0, &L[g * 4096 + c0]);
    gld16(At + g * 4096 + c1, &L[g * 4096 + c1]);
    gld16(Btl + g * 4096 + c0, &L[12288 + g * 4096 + c0]);
    gld16(Btl + g * 4096 + c1, &L[12288 + g * 4096 + c1]);
  }

  int abase = (q * 128 + wm + r) * 8;
  int bbase = (q * 128 + wn + r) * 8;

#pragma unroll
  for (int gi = 0; gi < nIter; ++gi) {
    const int rem = nIter - 1 - gi;  // groups still needed after this one
    if (rem >= 2)      __builtin_amdgcn_s_waitcnt(0x0f78);  // vmcnt(8)
    else if (rem == 1) __builtin_amdgcn_s_waitcnt(0x0f74);  // vmcnt(4)
    else               __builtin_amdgcn_s_waitcnt(0x0f70);  // vmcnt(0)
    __builtin_amdgcn_s_barrier();
    const int cur = gi % 3;
    const short* Asc = &L[cur * 4096];
    const short* Bsc = &L[12288 + cur * 4096];
    bf16x8 af[4], bfr[4];
#pragma unroll
    for (int mt = 0; mt < 4; ++mt)
      af[mt] = *(const bf16x8*)&Asc[abase + mt * 16 * 8];
#pragma unroll
    for (int nt = 0; nt < 4; ++nt)
      bfr[nt] = *(const bf16x8*)&Bsc[bbase + nt * 16 * 8];
#pragma unroll
    for (int mt = 0; mt < 4; ++mt)
#pragma unroll
      for (int nt = 0; nt < 4; ++nt)
        acc[mt][nt] = __builtin_amdgcn_mfma_f32_16x16x32_bf16(bfr[nt], af[mt], acc[mt][nt], 0, 0, 0);
    __builtin_amdgcn_s_waitcnt(0xc07f);  // lgkmcnt(0)
    __builtin_amdgcn_s_barrier();
    if (gi + 3 < nIter) {
      size_t kn = (size_t)(gi + 3) * 4096;
      gld16(At + kn + c0, &L[cur * 4096 + c0]);
      gld16(At + kn + c1, &L[cur * 4096 + c1]);
      gld16(Btl + kn + c0, &L[12288 + cur * 4096 + c0]);
      gld16(Btl + kn + c1, &L[12288 + cur * 4096 + c1]);
    }
  }

  float4 bias4[4];
#pragma unroll
  for (int nt = 0; nt < 4; ++nt) bias4[nt] = *(const float4*)&bias[n0 + wn + nt * 16 + q * 4];

  if (EPI == 0) {
    // stage tile to LDS [128][132] (pad: 2-way-free banks), then write head-major
    short* T = L;
#pragma unroll
    for (int mt = 0; mt < 4; ++mt) {
      int ml = wm + mt * 16 + r;
#pragma unroll
      for (int nt = 0; nt < 4; ++nt) {
        f32x4 v = acc[mt][nt];
        v[0] += bias4[nt].x; v[1] += bias4[nt].y; v[2] += bias4[nt].z; v[3] += bias4[nt].w;
        if (z < 2) { v[0] *= v[0]; v[1] *= v[1]; v[2] *= v[2]; v[3] *= v[3]; }
        short4 pk; pk.x = f2bf(v[0]); pk.y = f2bf(v[1]); pk.z = f2bf(v[2]); pk.w = f2bf(v[3]);
        *(short4*)&T[ml * 132 + wn + nt * 16 + q * 4] = pk;
      }
    }
    __syncthreads();
#pragma unroll
    for (int t2 = 0; t2 < 2; ++t2) {
      int task = tid + t2 * 256;
      int row = task & 127, hl = task >> 7;
      size_t obase = ((size_t)((n0 >> 5) + hl) * NROWS + m0 + row) * 32;
#pragma unroll
      for (int j = 0; j < 4; ++j)
        *(bf16x8*)&outz[obase + j * 8] = *(const bf16x8*)&T[row * 132 + hl * 32 + j * 8];
    }
  } else if (EPI == 1) {
#pragma unroll
    for (int mt = 0; mt < 4; ++mt) {
      int ml = wm + mt * 16 + r;
#pragma unroll
      for (int nt = 0; nt < 4; ++nt) {
        f32x4 v = acc[mt][nt];
        v[0] += bias4[nt].x; v[1] += bias4[nt].y; v[2] += bias4[nt].z; v[3] += bias4[nt].w;
#pragma unroll
        for (int e = 0; e < 4; ++e) v[e] = fast_gelu(v[e]);
        short4 o; o.x = f2bf(v[0]); o.y = f2bf(v[1]); o.z = f2bf(v[2]); o.w = f2bf(v[3]);
        int n = n0 + wn + nt * 16 + q * 4;
        size_t ti = ((size_t)blockIdx.x * (N >> 5) + (n >> 5)) * 4096 +
                    (size_t)(((n >> 3) & 3) << 10) + (ml << 3) + (n & 7);
        *(short4*)&outz[ti] = o;
      }
    }
  } else {
    // h += acc + bias, staged via LDS [128][68] f32, two 64-n rounds
    float* TF = (float*)L;
#pragma unroll
    for (int half = 0; half < 2; ++half) {
      __syncthreads();
      if ((w & 1) == half) {
#pragma unroll
        for (int mt = 0; mt < 4; ++mt) {
          int ml = wm + mt * 16 + r;
#pragma unroll
          for (int nt = 0; nt < 4; ++nt) {
            f32x4 v = acc[mt][nt];
            v[0] += bias4[nt].x; v[1] += bias4[nt].y; v[2] += bias4[nt].z; v[3] += bias4[nt].w;
            *(f32x4*)&TF[ml * 68 + nt * 16 + q * 4] = v;
          }
        }
      }
      __syncthreads();
      int row = tid >> 1, col = (tid & 1) * 32;
      size_t hoff = (size_t)(m0 + row) * N + n0 + half * 64 + col;
#pragma unroll
      for (int j = 0; j < 8; ++j) {
        float4 add = *(const float4*)&TF[row * 68 + col + j * 4];
        float4 cur4 = *(float4*)&outf[hoff + j * 4];
        cur4.x += add.x; cur4.y += add.y; cur4.z += add.z; cur4.w += add.w;
        *(float4*)&outf[hoff + j * 4] = cur4;
      }
    }
  }
}

// ---------------- fused FFN: h += gelu(hn@WU+bU)@WV + bV ---------------------
// One block per 128-row strip (256 blocks = 1/CU), 8 waves, R11 structure with
// HALVED step count: 32 steps (8 slices x {2 up + 2 down}) on 32KB slots,
// 2-slot double buffer, uniform 4 gld16/thread per slot, constant vmcnt(4).
// Up-step: 4 K-blocks (32 MFMA/wave); down-step: 2 kbg (32 MFMA/wave).
// bU in regs (b4[2]), loaded BEFORE the slot-issue at end of up-step p0 so the
// next vmcnt(4) drains [older slot (4) + b4 (2)] leaving the newest slot (4).
// LDS (shorts): A[0,32768) mid[32768,49152) slot0@49152 slot1@65536 = 160KB.
__global__ __launch_bounds__(512) void ffn_fused(
    const short* __restrict__ A, const short* __restrict__ TUw,
    const short* __restrict__ TVw, const float* __restrict__ bUp,
    const float* __restrict__ bVp, float* __restrict__ h) {
  __shared__ __align__(16) short L[81920];  // 160KB exactly
  int tid = threadIdx.x;
  int lane = tid & 63, w = tid >> 6;
  int q = lane >> 4, r = lane & 15;
  int wmU = (w >> 2) * 64, wnU = (w & 3) * 32;   // up: wave = 64 rows x 32 f
  int wmD = (w >> 2) * 64, wnD = (w & 3) * 64;   // down: wave = 64 rows x 64 d
  const short* At = A + (size_t)blockIdx.x * 32768;

  // A strip -> LDS: 64KB contiguous tiled layout, 8 gld16/thread (oldest vmem)
#pragma unroll
  for (int i = 0; i < 8; ++i)
    gld16(At + (i * 512 + tid) * 8, &L[(i * 512 + tid) * 8]);

  auto issueFor = [&](int t) {  // stage 32KB slot(t) into buf[t&1]; 4 gld16/thread
    short* dst = &L[49152 + (t & 1) * 16384];
    int ss = t >> 2, pp = t & 3;
    if (pp < 2) {  // up: WU tiles ss*8 + pp*4 .. +3 (contiguous 32KB)
      const short* g0 = TUw + ((size_t)ss * 8 + pp * 4) * 4096;
#pragma unroll
      for (int i = 0; i < 4; ++i)
        gld16(g0 + (i * 512 + tid) * 8, dst + (i * 512 + tid) * 8);
    } else {       // down: kbg pair; per kbg: WV tiles (kbg) and (32+kbg)
      int kbg0 = ss * 4 + (pp - 2) * 2;
#pragma unroll
      for (int kl = 0; kl < 2; ++kl) {
        gld16(TVw + (size_t)(kbg0 + kl) * 4096 + tid * 8,
              dst + kl * 8192 + tid * 8);
        gld16(TVw + (size_t)(32 + kbg0 + kl) * 4096 + tid * 8,
              dst + kl * 8192 + 4096 + tid * 8);
      }
    }
  };

  issueFor(0); issueFor(1);

  f32x4 vzero = {0.f, 0.f, 0.f, 0.f};
  f32x4 accm[4][2], acco[4][4];
#pragma unroll
  for (int mt = 0; mt < 4; ++mt) {
#pragma unroll
    for (int nt = 0; nt < 2; ++nt) accm[mt][nt] = vzero;
#pragma unroll
    for (int nt = 0; nt < 4; ++nt) acco[mt][nt] = vzero;
  }
  float4 b4[2];

  auto slice = [&](int s, auto lastc) {
    constexpr bool LAST = decltype(lastc)::value;
    // ---- up steps p=0,1: slot(s*4+p) holds WU kb = 4p..4p+3 ----
#pragma unroll
    for (int p = 0; p < 2; ++p) {
      int sig = s * 4 + p;
      __builtin_amdgcn_s_waitcnt(0x0f74);  // vmcnt(4)
      __builtin_amdgcn_s_barrier();
      const short* Ws = &L[49152 + (sig & 1) * 16384];
#pragma unroll
      for (int kl = 0; kl < 4; ++kl) {
        int kb = p * 4 + kl;
        bf16x8 af[4], bfr[2];
#pragma unroll
        for (int mt = 0; mt < 4; ++mt)
          af[mt] = *(const bf16x8*)&L[kb * 4096 + (q * 128 + wmU + mt * 16 + r) * 8];
#pragma unroll
        for (int nt = 0; nt < 2; ++nt)
          bfr[nt] = *(const bf16x8*)&Ws[kl * 4096 + (q * 128 + wnU + nt * 16 + r) * 8];
#pragma unroll
        for (int mt = 0; mt < 4; ++mt)
#pragma unroll
          for (int nt = 0; nt < 2; ++nt)
            accm[mt][nt] = __builtin_amdgcn_mfma_f32_16x16x32_bf16(
                bfr[nt], af[mt], accm[mt][nt], 0, 0, 0);
      }
      if (p == 1) {  // slice's K done: bias + gelu + pack -> mid (A-tile fmt)
#pragma unroll
        for (int mt = 0; mt < 4; ++mt) {
          int row = wmU + mt * 16 + r;
#pragma unroll
          for (int nt = 0; nt < 2; ++nt) {
            f32x4 v = accm[mt][nt];
            float4 bb = b4[nt];
            v[0] += bb.x; v[1] += bb.y; v[2] += bb.z; v[3] += bb.w;
            short4 pk;
            pk.x = f2bf(fast_gelu(v[0])); pk.y = f2bf(fast_gelu(v[1]));
            pk.z = f2bf(fast_gelu(v[2])); pk.w = f2bf(fast_gelu(v[3]));
            int kc8 = 2 * nt + (q >> 1);  // f = wnU + nt*16 + q*4 + e
            *(short4*)&L[32768 + (w & 3) * 4096 + (kc8 * 128 + row) * 8 + (q & 1) * 4] = pk;
            accm[mt][nt] = vzero;
          }
        }
      }
      __builtin_amdgcn_s_waitcnt(0xc07f);  // lgkmcnt(0)
      __builtin_amdgcn_s_barrier();
      if (p == 0) {  // bU for this slice BEFORE the issue: next vmcnt(4)
                     // drains [slot sig+1 (4) + b4 (2)], leaving slot sig+2.
        b4[0] = *(const float4*)&bUp[s * 128 + wnU + q * 4];
        b4[1] = *(const float4*)&bUp[s * 128 + wnU + 16 + q * 4];
      }
      if (sig + 2 < 32) issueFor(sig + 2);
    }
    // ---- down steps p2=0,1: slot(s*4+2+p2) = kbg pair ----
#pragma unroll
    for (int p2 = 0; p2 < 2; ++p2) {
      int sig = s * 4 + 2 + p2;
      if (LAST && p2 == 1) __builtin_amdgcn_s_waitcnt(0x0f70);  // vmcnt(0)
      else                 __builtin_amdgcn_s_waitcnt(0x0f74);  // vmcnt(4)
      __builtin_amdgcn_s_barrier();
      const short* Ws = &L[49152 + (sig & 1) * 16384];
#pragma unroll
      for (int kl = 0; kl < 2; ++kl) {
        int mtile = p2 * 2 + kl;  // mid tile (f-block) 0..3
        bf16x8 am[4], bvf[4];
#pragma unroll
        for (int mt = 0; mt < 4; ++mt)
          am[mt] = *(const bf16x8*)&L[32768 + mtile * 4096 + (q * 128 + wmD + mt * 16 + r) * 8];
#pragma unroll
        for (int nt = 0; nt < 4; ++nt)
          bvf[nt] = *(const bf16x8*)&Ws[kl * 8192 + (wnD >> 7) * 4096 +
                                        (q * 128 + (wnD & 127) + nt * 16 + r) * 8];
#pragma unroll
        for (int mt = 0; mt < 4; ++mt)
#pragma unroll
          for (int nt = 0; nt < 4; ++nt)
            acco[mt][nt] = __builtin_amdgcn_mfma_f32_16x16x32_bf16(
                bvf[nt], am[mt], acco[mt][nt], 0, 0, 0);
      }
      __builtin_amdgcn_s_waitcnt(0xc07f);  // lgkmcnt(0)
      __builtin_amdgcn_s_barrier();
      if (sig + 2 < 32) issueFor(sig + 2);
    }
  };

  for (int s = 0; s < 7; ++s) slice(s, FalseT{});
  slice(7, TrueT{});

  // epilogue (R11): out += bV; stage [128][260] f32 in LDS; FULL-ROW h RMW
  float4 bv4[4];
#pragma unroll
  for (int nt = 0; nt < 4; ++nt) bv4[nt] = *(const float4*)&bVp[wnD + nt * 16 + q * 4];
  float* TF = (float*)L;
#pragma unroll
  for (int mt = 0; mt < 4; ++mt) {
    int row = wmD + mt * 16 + r;
#pragma unroll
    for (int nt = 0; nt < 4; ++nt) {
      f32x4 v = acco[mt][nt];
      v[0] += bv4[nt].x; v[1] += bv4[nt].y; v[2] += bv4[nt].z; v[3] += bv4[nt].w;
      *(f32x4*)&TF[row * 260 + wnD + nt * 16 + q * 4] = v;
    }
  }
  __syncthreads();
  size_t hbase = ((size_t)blockIdx.x * 128 + w * 16) * DD;
#pragma unroll
  for (int j = 0; j < 16; ++j) {
    float4 add = *(const float4*)&TF[(w * 16 + j) * 260 + lane * 4];
    float4 c4 = *(float4*)&h[hbase + (size_t)j * DD + lane * 4];
    c4.x += add.x; c4.y += add.y; c4.z += add.z; c4.w += add.w;
    *(float4*)&h[hbase + (size_t)j * DD + lane * 4] = c4;
  }
}

// ---------------- attention A1: per (b,h,chunk) S_c = K^T V, z_c = sum k ------
// q/k/v head-major: [head][32768][32]
__global__ __launch_bounds__(256) void attn_chunk_kv(
    const short* __restrict__ Kb, const short* __restrict__ Vb,
    float* __restrict__ St, float* __restrict__ Zc) {
  __shared__ short Kt[4][32 * 72];
  __shared__ short Vt[4][32 * 72];
  int wid = threadIdx.x >> 6;
  int blk = blockIdx.x * 4 + wid;
  int c = blk & (NC - 1), bh = blk >> 5;
  int b = bh >> 3, hh = bh & 7;
  int lane = threadIdx.x & 63, q = lane >> 4, r = lane & 15;
  size_t rowbase = ((size_t)hh * NROWS + b * GG + c * CS + lane) * 32;
#pragma unroll
  for (int j = 0; j < 4; ++j) {
    bf16x8 kv = *(const bf16x8*)&Kb[rowbase + j * 8];
    bf16x8 vv = *(const bf16x8*)&Vb[rowbase + j * 8];
#pragma unroll
    for (int e = 0; e < 8; ++e) {
      Kt[wid][(j * 8 + e) * 72 + lane] = kv[e];
      Vt[wid][(j * 8 + e) * 72 + lane] = vv[e];
    }
  }
  __syncthreads();
  f32x4 vzero = {0.f, 0.f, 0.f, 0.f};
  f32x4 acc[2][2];
#pragma unroll
  for (int i = 0; i < 2; ++i)
#pragma unroll
    for (int j = 0; j < 2; ++j) acc[i][j] = vzero;
#pragma unroll
  for (int ks = 0; ks < 2; ++ks) {
    bf16x8 afr[2], bfr[2];
#pragma unroll
    for (int mt = 0; mt < 2; ++mt) afr[mt] = *(const bf16x8*)&Kt[wid][(mt * 16 + r) * 72 + ks * 32 + q * 8];
#pragma unroll
    for (int nt = 0; nt < 2; ++nt) bfr[nt] = *(const bf16x8*)&Vt[wid][(nt * 16 + r) * 72 + ks * 32 + q * 8];
#pragma unroll
    for (int mt = 0; mt < 2; ++mt)
#pragma unroll
      for (int nt = 0; nt < 2; ++nt)
        acc[mt][nt] = __builtin_amdgcn_mfma_f32_16x16x32_bf16(afr[mt], bfr[nt], acc[mt][nt], 0, 0, 0);
  }
  float* stp = St + ((size_t)bh * NC + c) * 1024;
#pragma unroll
  for (int mt = 0; mt < 2; ++mt)
#pragma unroll
    for (int nt = 0; nt < 2; ++nt)
      *(f32x4*)&stp[(nt * 16 + r) * 32 + mt * 16 + q * 4] = acc[mt][nt];  // St[d][f]
  if (lane < 32) {
    float s = 0.f;
#pragma unroll
    for (int j = 0; j < 8; ++j) {
      bf16x8 kr = *(const bf16x8*)&Kt[wid][lane * 72 + j * 8];
#pragma unroll
      for (int e = 0; e < 8; ++e) s += bf2f(kr[e]);
    }
    Zc[((size_t)bh * NC + c) * 32 + lane] = s;
  }
}

// ---------------- attention A2: exclusive prefix over chunks ------------------
__global__ __launch_bounds__(1024) void attn_prefix(float* __restrict__ St, float* __restrict__ Zc) {
  int bh = blockIdx.x, i = threadIdx.x;
  float run = 0.f;
  float* p = St + (size_t)bh * NC * 1024 + i;
#pragma unroll
  for (int c = 0; c < NC; ++c) { float t = p[(size_t)c * 1024]; p[(size_t)c * 1024] = run; run += t; }
  if (i < 32) {
    float rz = 0.f;
    float* pz = Zc + (size_t)bh * NC * 32 + i;
#pragma unroll
    for (int c = 0; c < NC; ++c) { float t = pz[c * 32]; pz[c * 32] = rz; rz += t; }
  }
}

// ---------------- attention B: intra-chunk + apply, h += out ------------------
__global__ __launch_bounds__(256) void attn_intra(
    const short* __restrict__ Qb, const short* __restrict__ Kb,
    const short* __restrict__ Vb, const float* __restrict__ St,
    const float* __restrict__ Zc, float* __restrict__ h) {
  __shared__ short P[4][64 * 72];
  __shared__ short Vt[4][32 * 72];
  __shared__ float den[4][64];
  int wid = threadIdx.x >> 6;
  int blk = blockIdx.x * 4 + wid;
  int c = blk & (NC - 1), bh = blk >> 5;
  int b = bh >> 3, hh = bh & 7;
  int lane = threadIdx.x & 63, q = lane >> 4, r = lane & 15;
  size_t hrow0 = (size_t)b * GG + c * CS;                 // rows in h (row-major)
  size_t qrow0 = (size_t)hh * NROWS + b * GG + c * CS;    // rows in head-major qkv

  const float* zp = Zc + ((size_t)bh * NC + c) * 32;
  float qz = 0.f;
  {
    size_t qoff = (qrow0 + lane) * 32;
#pragma unroll
    for (int j = 0; j < 4; ++j) {
      bf16x8 qv = *(const bf16x8*)&Qb[qoff + j * 8];
#pragma unroll
      for (int e = 0; e < 8; ++e) qz += bf2f(qv[e]) * zp[j * 8 + e];
    }
  }
  den[wid][lane] = qz;

  {
    size_t voff = (qrow0 + lane) * 32;
#pragma unroll
    for (int j = 0; j < 4; ++j) {
      bf16x8 vv = *(const bf16x8*)&Vb[voff + j * 8];
#pragma unroll
      for (int e = 0; e < 8; ++e) Vt[wid][(j * 8 + e) * 72 + lane] = vv[e];
    }
  }

  bf16x8 ak[4], bqf[4];
#pragma unroll
  for (int t4 = 0; t4 < 4; ++t4) {
    ak[t4]  = *(const bf16x8*)&Kb[(qrow0 + t4 * 16 + r) * 32 + q * 8];
    bqf[t4] = *(const bf16x8*)&Qb[(qrow0 + t4 * 16 + r) * 32 + q * 8];
  }
  f32x4 vzero = {0.f, 0.f, 0.f, 0.f};
  f32x4 pacc[4][4];
#pragma unroll
  for (int mt = 0; mt < 4; ++mt)
#pragma unroll
    for (int nt = 0; nt < 4; ++nt)
      pacc[mt][nt] = __builtin_amdgcn_mfma_f32_16x16x32_bf16(ak[mt], bqf[nt], vzero, 0, 0, 0);

  float rs[4] = {0.f, 0.f, 0.f, 0.f};
#pragma unroll
  for (int nt = 0; nt < 4; ++nt) {
    int t = nt * 16 + r;
#pragma unroll
    for (int mt = 0; mt < 4; ++mt) {
      short4 pk;
#pragma unroll
      for (int rr = 0; rr < 4; ++rr) {
        int s = mt * 16 + q * 4 + rr;
        float pv = (s <= t) ? pacc[mt][nt][rr] : 0.f;
        rs[nt] += pv;
        ((short*)&pk)[rr] = f2bf(pv);
      }
      *(short4*)&P[wid][t * 72 + mt * 16 + q * 4] = pk;
    }
  }
#pragma unroll
  for (int nt = 0; nt < 4; ++nt) {
    rs[nt] += __shfl_xor(rs[nt], 16);
    rs[nt] += __shfl_xor(rs[nt], 32);
  }
  __syncthreads();
  if (lane < 16) {
#pragma unroll
    for (int nt = 0; nt < 4; ++nt) den[wid][nt * 16 + lane] += rs[nt];
  }
  __syncthreads();

  f32x4 oacc[4][2];
#pragma unroll
  for (int mt = 0; mt < 4; ++mt)
#pragma unroll
    for (int nt2 = 0; nt2 < 2; ++nt2) oacc[mt][nt2] = vzero;
  const float* stp = St + ((size_t)bh * NC + c) * 1024;
#pragma unroll
  for (int nt2 = 0; nt2 < 2; ++nt2) {
    float4 s0 = *(const float4*)&stp[(nt2 * 16 + r) * 32 + q * 8];
    float4 s1 = *(const float4*)&stp[(nt2 * 16 + r) * 32 + q * 8 + 4];
    bf16x8 bs;
    bs[0] = f2bf(s0.x); bs[1] = f2bf(s0.y); bs[2] = f2bf(s0.z); bs[3] = f2bf(s0.w);
    bs[4] = f2bf(s1.x); bs[5] = f2bf(s1.y); bs[6] = f2bf(s1.z); bs[7] = f2bf(s1.w);
#pragma unroll
    for (int mt = 0; mt < 4; ++mt)
      oacc[mt][nt2] = __builtin_amdgcn_mfma_f32_16x16x32_bf16(bqf[mt], bs, oacc[mt][nt2], 0, 0, 0);
  }
#pragma unroll
  for (int ks = 0; ks < 2; ++ks) {
    bf16x8 ap[4];
#pragma unroll
    for (int mt = 0; mt < 4; ++mt)
      ap[mt] = *(const bf16x8*)&P[wid][(mt * 16 + r) * 72 + ks * 32 + q * 8];
#pragma unroll
    for (int nt2 = 0; nt2 < 2; ++nt2) {
      bf16x8 bv_ = *(const bf16x8*)&Vt[wid][(nt2 * 16 + r) * 72 + ks * 32 + q * 8];
#pragma unroll
      for (int mt = 0; mt < 4; ++mt)
        oacc[mt][nt2] = __builtin_amdgcn_mfma_f32_16x16x32_bf16(ap[mt], bv_, oacc[mt][nt2], 0, 0, 0);
    }
  }

#pragma unroll
  for (int mt = 0; mt < 4; ++mt) {
#pragma unroll
    for (int rr = 0; rr < 4; ++rr) {
      int t = mt * 16 + q * 4 + rr;
      float inv = 1.0f / (den[wid][t] + 1e-16f);
#pragma unroll
      for (int nt2 = 0; nt2 < 2; ++nt2) {
        int d = nt2 * 16 + r;
        size_t off = (hrow0 + t) * DD + hh * 32 + d;
        h[off] += oacc[mt][nt2][rr] * inv;
      }
    }
  }
}

// ---------------- final projection -------------------------------------------
__global__ __launch_bounds__(256) void out_proj(
    const float* __restrict__ h, const float* __restrict__ Wout,
    const float* __restrict__ bout, float* __restrict__ out) {
  int row = blockIdx.x * 4 + (threadIdx.x >> 6);
  int lane = threadIdx.x & 63;
  float4 a = *(const float4*)&h[(size_t)row * DD + lane * 4];
  float4 w = *(const float4*)&Wout[lane * 4];
  float s = a.x * w.x + a.y * w.y + a.z * w.z + a.w * w.w;
#pragma unroll
  for (int o = 1; o < 64; o <<= 1) s += __shfl_xor(s, o);
  if (lane == 0) out[row] = s + bout[0];
}

extern "C" void kernel_launch(void* const* d_in, const int* in_sizes, int n_in,
                              void* d_out, int out_size, void* d_ws, size_t ws_size,
                              hipStream_t stream) {
  const float* x    = (const float*)d_in[0];
  const float* ge   = (const float*)d_in[1];
  const float* invf = (const float*)d_in[2];
  const float* Wq   = (const float*)d_in[3];
  const float* bq   = (const float*)d_in[4];
  const float* Wk   = (const float*)d_in[5];
  const float* bk   = (const float*)d_in[6];
  const float* Wv   = (const float*)d_in[7];
  const float* bv   = (const float*)d_in[8];
  const float* ln1g = (const float*)d_in[9];
  const float* ln1b = (const float*)d_in[10];
  const float* ln2g = (const float*)d_in[11];
  const float* ln2b = (const float*)d_in[12];
  const float* WU   = (const float*)d_in[13];
  const float* bU   = (const float*)d_in[14];
  const float* WV   = (const float*)d_in[15];
  const float* bV   = (const float*)d_in[16];
  const float* Wout = (const float*)d_in[17];
  const float* bout = (const float*)d_in[18];
  float* out = (float*)d_out;

  char* ws = (char*)d_ws;
  float* h   = (float*)(ws + 0);            // 33.5 MB
  short* hn  = (short*)(ws + 33554432);     // 16.8 MB (tiled)
  char*  R   = ws + 50331648;               // shared region
  short* qb  = (short*)(R + 0);             // head-major [8][32768][32]
  short* kb  = (short*)(R + 16777216);
  short* vb  = (short*)(R + 33554432);
  float* St  = (float*)(R + 50331648);
  float* Zc  = (float*)(R + 67108864);
  char*  WT  = R + 67633152;
  short* TQ  = (short*)(WT + 0);
  short* TK  = (short*)(WT + 524288);
  short* TVq = (short*)(WT + 1048576);
  short* TU  = (short*)(WT + 1572864);
  short* TVd = (short*)(WT + 3670016);

  prep_weights<<<dim3(1024, 4, 5), 256, 0, stream>>>(Wq, Wk, Wv, WU, WV, TQ, TK, TVq, TU, TVd);
  embed_kernel<<<NROWS / 4, 256, 0, stream>>>(x, ge, invf, h);

  for (int l = 0; l < 4; ++l) {
    ln_tiled<<<NROWS / 32, 256, 0, stream>>>(h, ln1g + l * 256, ln1b + l * 256, hn);
    gemm_t<256, 0><<<dim3(256, 2, 3), 256, 0, stream>>>(
        hn, TQ + l * 65536, TK + l * 65536, TVq + l * 65536,
        bq + l * 256, bk + l * 256, bv + l * 256,
        qb, kb, vb, nullptr, 256);
    attn_chunk_kv<<<1024, 256, 0, stream>>>(kb, vb, St, Zc);
    attn_prefix<<<128, 1024, 0, stream>>>(St, Zc);
    attn_intra<<<1024, 256, 0, stream>>>(qb, kb, vb, St, Zc, h);
    ln_tiled<<<NROWS / 32, 256, 0, stream>>>(h, ln2g + l * 256, ln2b + l * 256, hn);
    ffn_fused<<<256, 512, 0, stream>>>(hn, TU + l * 262144, TVd + l * 262144,
                                       bU + l * 1024, bV + l * 256, h);
  }
  out_proj<<<NROWS / 4, 256, 0, stream>>>(h, Wout, bout, out);
}

// Round 9
// 753.227 us; speedup vs baseline: 1.0456x; 1.0042x over previous
//
#include <hip/hip_runtime.h>
#include <math.h>

// ExpressionPerformer: B=16,G=2048,D=256,H=8,dh=32,FFN=1024,L=4
// Round-18 (= R17 + two independent changes):
//  - T5: s_setprio(1/0) around the MFMA compute phase in ffn_fused and gemm_t.
//    Both are counted-vmcnt phase-split loops (never drain to 0 mid-loop) --
//    the regime where m218b measured +21-25%. One inst pair per step.
//  - attn_intra: block regrouped to 4 ADJACENT heads of one (b,c) chunk
//    (hh = hg*4 + wid); epilogue h+= staged through LDS (reuse of dead P
//    region, 16B-aligned) then 512B-contiguous half-row float4 RMW.
//    Replaces the scalar 8B-granule scattered h[off]+= (partial-line writes,
//    same disease as R13-16's 4x write amplification).
//  - everything else identical to R17 (64.6us ffn, clean counters).

#define GG 2048
#define DD 256
#define NROWS 32768
#define NC 32
#define CS 64

typedef __attribute__((ext_vector_type(8))) short bf16x8;
typedef __attribute__((ext_vector_type(4))) float f32x4;

struct FalseT { static constexpr bool value = false; };
struct TrueT  { static constexpr bool value = true;  };

__device__ __forceinline__ short f2bf(float f) {
  union { float f; unsigned u; } v; v.f = f;
  unsigned r = v.u + 0x7FFFu + ((v.u >> 16) & 1u);
  return (short)(r >> 16);
}
__device__ __forceinline__ float bf2f(short s) {
  union { unsigned u; float f; } v; v.u = ((unsigned)(unsigned short)s) << 16;
  return v.f;
}
__device__ __forceinline__ void gld16(const short* g, short* l) {
  __builtin_amdgcn_global_load_lds(
      (const __attribute__((address_space(1))) void*)g,
      (__attribute__((address_space(3))) void*)l, 16, 0, 0);
}
__device__ __forceinline__ float fast_gelu(float x) {
  float y = 1.595769122f * (x + 0.044715f * x * x * x);
  return x / (1.0f + __expf(-y));
}

// ---------------- embed ------------------------------------------------------
__global__ __launch_bounds__(256) void embed_kernel(
    const float* __restrict__ x, const float* __restrict__ ge,
    const float* __restrict__ invf, float* __restrict__ h) {
  int bg = blockIdx.x * 4 + (threadIdx.x >> 6);
  int g = bg & (GG - 1);
  int lane = threadIdx.x & 63;
  float xv = x[bg];
  int d = lane * 4;
  float4 e;
  if (lane < 32) {
    float4 f = *(const float4*)&invf[d];
    e.x = sinf(xv * f.x); e.y = sinf(xv * f.y);
    e.z = sinf(xv * f.z); e.w = sinf(xv * f.w);
  } else {
    float4 f = *(const float4*)&invf[d - 128];
    e.x = cosf(xv * f.x); e.y = cosf(xv * f.y);
    e.z = cosf(xv * f.z); e.w = cosf(xv * f.w);
  }
  if (xv == -10.0f) { e.x = 0.f; e.y = 0.f; e.z = 0.f; e.w = 0.f; }
  float4 gv = *(const float4*)&ge[(size_t)g * DD + d];
  float4 o; o.x = gv.x + e.x; o.y = gv.y + e.y; o.z = gv.z + e.z; o.w = gv.w + e.w;
  *(float4*)&h[(size_t)bg * DD + d] = o;
}

// ---------------- layernorm -> TILED bf16 ------------------------------------
__global__ __launch_bounds__(256) void ln_tiled(
    const float* __restrict__ h, const float* __restrict__ gamma,
    const float* __restrict__ beta, short* __restrict__ outT) {
  __shared__ float mean_s[32], rstd_s[32];
  __shared__ float gls[256], bls[256];
  int r0 = blockIdx.x * 32;
  int tid = threadIdx.x;
  gls[tid] = gamma[tid]; bls[tid] = beta[tid];
  {
    int row = tid >> 3, seg = tid & 7;
    const float4* hp = (const float4*)(h + (size_t)(r0 + row) * DD + seg * 32);
    float s = 0.f, s2 = 0.f;
#pragma unroll
    for (int i = 0; i < 8; ++i) {
      float4 v = hp[i];
      s += v.x + v.y + v.z + v.w;
      s2 += v.x * v.x + v.y * v.y + v.z * v.z + v.w * v.w;
    }
    s += __shfl_xor(s, 1); s += __shfl_xor(s, 2); s += __shfl_xor(s, 4);
    s2 += __shfl_xor(s2, 1); s2 += __shfl_xor(s2, 2); s2 += __shfl_xor(s2, 4);
    if (seg == 0) {
      float mn = s * (1.0f / 256.0f);
      mean_s[row] = mn;
      rstd_s[row] = rsqrtf(s2 * (1.0f / 256.0f) - mn * mn + 1e-5f);
    }
  }
  __syncthreads();
  int row = tid & 31, kc8 = (tid >> 5) & 3, half = tid >> 7;
  float mn = mean_s[row], rs = rstd_s[row];
  size_t hrow = (size_t)(r0 + row) * DD;
  int trow = (r0 & 127) + row;
  short* tb = outT + (size_t)(r0 >> 7) * 8 * 4096 + (kc8 * 128 + trow) * 8;
#pragma unroll
  for (int j = 0; j < 4; ++j) {
    int kb = half * 4 + j;
    int k0 = kb * 32 + kc8 * 8;
    float4 x0 = *(const float4*)&h[hrow + k0];
    float4 x1 = *(const float4*)&h[hrow + k0 + 4];
    float4 g0 = *(const float4*)&gls[k0], g1 = *(const float4*)&gls[k0 + 4];
    float4 b0 = *(const float4*)&bls[k0], b1 = *(const float4*)&bls[k0 + 4];
    bf16x8 aw;
    aw[0] = f2bf((x0.x - mn) * rs * g0.x + b0.x);
    aw[1] = f2bf((x0.y - mn) * rs * g0.y + b0.y);
    aw[2] = f2bf((x0.z - mn) * rs * g0.z + b0.z);
    aw[3] = f2bf((x0.w - mn) * rs * g0.w + b0.w);
    aw[4] = f2bf((x1.x - mn) * rs * g1.x + b1.x);
    aw[5] = f2bf((x1.y - mn) * rs * g1.y + b1.y);
    aw[6] = f2bf((x1.z - mn) * rs * g1.z + b1.z);
    aw[7] = f2bf((x1.w - mn) * rs * g1.w + b1.w);
    *(bf16x8*)&tb[(size_t)kb * 4096] = aw;
  }
}

// ---------------- weight convert+transpose -> TILED --------------------------
__global__ __launch_bounds__(256) void prep_weights(
    const float* __restrict__ Wq, const float* __restrict__ Wk,
    const float* __restrict__ Wv, const float* __restrict__ WU,
    const float* __restrict__ WV,
    short* __restrict__ TQ, short* __restrict__ TK, short* __restrict__ TV,
    short* __restrict__ TU, short* __restrict__ TVd) {
  int zz = blockIdx.z, l = blockIdx.y;
  const float* src; short* dst; int Kd, Nd;
  if (zz == 0) { src = Wq; dst = TQ; Kd = 256; Nd = 256; }
  else if (zz == 1) { src = Wk; dst = TK; Kd = 256; Nd = 256; }
  else if (zz == 2) { src = Wv; dst = TV; Kd = 256; Nd = 256; }
  else if (zz == 3) { src = WU; dst = TU; Kd = 256; Nd = 1024; }
  else { src = WV; dst = TVd; Kd = 1024; Nd = 256; }
  int tot = Kd * Nd;
  int e = blockIdx.x * 256 + threadIdx.x;
  if (e >= tot) return;
  int t = e >> 12;
  int cslot = (e >> 3) & 511;
  int elem = e & 7;
  int kc8 = cslot >> 7, rn = cslot & 127;
  int nKb = Kd >> 5;
  int nt = t / nKb, kb = t - nt * nKb;
  int n = nt * 128 + rn, k = kb * 32 + kc8 * 8 + elem;
  dst[(size_t)l * tot + e] = f2bf(src[(size_t)l * tot + (size_t)k * Nd + n]);
}

// ---------------- bf16 MFMA GEMM (tiled operands, compile-time K) -------------
// 3-buffer rolling pipeline, fully unrolled. EPI 0: square(z<2), HEAD-MAJOR
// bf16 out via LDS transpose (QKV path). T5: setprio around compute phase.
template <int K, int EPI>
__global__ __launch_bounds__(256) void gemm_t(
    const short* __restrict__ A, const short* __restrict__ B0,
    const short* __restrict__ B1, const short* __restrict__ B2,
    const float* __restrict__ bias0, const float* __restrict__ bias1,
    const float* __restrict__ bias2,
    short* __restrict__ o0, short* __restrict__ o1, short* __restrict__ o2,
    float* __restrict__ outf, int N) {
  __shared__ __align__(16) short L[24576];  // 48KB: As g @ g*4096, Bs g @ 12288+g*4096
  constexpr int nIter = K / 32;
  int z = blockIdx.z;
  const short* Bt = (z == 0) ? B0 : (z == 1) ? B1 : B2;
  const float* bias = (z == 0) ? bias0 : (z == 1) ? bias1 : bias2;
  short* outz = (z == 0) ? o0 : (z == 1) ? o1 : o2;
  int m0 = blockIdx.x * 128, n0 = blockIdx.y * 128;
  int tid = threadIdx.x;
  int lane = tid & 63, w = tid >> 6;
  int q = lane >> 4, r = lane & 15;
  int wm = (w >> 1) * 64, wn = (w & 1) * 64;
  const short* At = A + (size_t)blockIdx.x * nIter * 4096;
  const short* Btl = Bt + (size_t)blockIdx.y * nIter * 4096;
  f32x4 vzero = {0.f, 0.f, 0.f, 0.f};
  f32x4 acc[4][4];
#pragma unroll
  for (int i = 0; i < 4; ++i)
#pragma unroll
    for (int j = 0; j < 4; ++j) acc[i][j] = vzero;

  int c0 = tid * 8, c1 = (tid + 256) * 8;
  // prologue: groups 0,1,2
#pragma unroll
  for (int g = 0; g < 3; ++g) {
    gld16(At + g * 4096 + c0, &L[g * 4096 + c0]);
    gld16(At + g * 4096 + c1, &L[g * 4096 + c1]);
    gld16(Btl + g * 4096 + c0, &L[12288 + g * 4096 + c0]);
    gld16(Btl + g * 4096 + c1, &L[12288 + g * 4096 + c1]);
  }

  int abase = (q * 128 + wm + r) * 8;
  int bbase = (q * 128 + wn + r) * 8;

#pragma unroll
  for (int gi = 0; gi < nIter; ++gi) {
    const int rem = nIter - 1 - gi;  // groups still needed after this one
    if (rem >= 2)      __builtin_amdgcn_s_waitcnt(0x0f78);  // vmcnt(8)
    else if (rem == 1) __builtin_amdgcn_s_waitcnt(0x0f74);  // vmcnt(4)
    else               __builtin_amdgcn_s_waitcnt(0x0f70);  // vmcnt(0)
    __builtin_amdgcn_s_barrier();
    __builtin_amdgcn_s_setprio(1);
    const int cur = gi % 3;
    const short* Asc = &L[cur * 4096];
    const short* Bsc = &L[12288 + cur * 4096];
    bf16x8 af[4], bfr[4];
#pragma unroll
    for (int mt = 0; mt < 4; ++mt)
      af[mt] = *(const bf16x8*)&Asc[abase + mt * 16 * 8];
#pragma unroll
    for (int nt = 0; nt < 4; ++nt)
      bfr[nt] = *(const bf16x8*)&Bsc[bbase + nt * 16 * 8];
#pragma unroll
    for (int mt = 0; mt < 4; ++mt)
#pragma unroll
      for (int nt = 0; nt < 4; ++nt)
        acc[mt][nt] = __builtin_amdgcn_mfma_f32_16x16x32_bf16(bfr[nt], af[mt], acc[mt][nt], 0, 0, 0);
    __builtin_amdgcn_s_setprio(0);
    __builtin_amdgcn_s_waitcnt(0xc07f);  // lgkmcnt(0)
    __builtin_amdgcn_s_barrier();
    if (gi + 3 < nIter) {
      size_t kn = (size_t)(gi + 3) * 4096;
      gld16(At + kn + c0, &L[cur * 4096 + c0]);
      gld16(At + kn + c1, &L[cur * 4096 + c1]);
      gld16(Btl + kn + c0, &L[12288 + cur * 4096 + c0]);
      gld16(Btl + kn + c1, &L[12288 + cur * 4096 + c1]);
    }
  }

  float4 bias4[4];
#pragma unroll
  for (int nt = 0; nt < 4; ++nt) bias4[nt] = *(const float4*)&bias[n0 + wn + nt * 16 + q * 4];

  if (EPI == 0) {
    // stage tile to LDS [128][132] (pad: 2-way-free banks), then write head-major
    short* T = L;
#pragma unroll
    for (int mt = 0; mt < 4; ++mt) {
      int ml = wm + mt * 16 + r;
#pragma unroll
      for (int nt = 0; nt < 4; ++nt) {
        f32x4 v = acc[mt][nt];
        v[0] += bias4[nt].x; v[1] += bias4[nt].y; v[2] += bias4[nt].z; v[3] += bias4[nt].w;
        if (z < 2) { v[0] *= v[0]; v[1] *= v[1]; v[2] *= v[2]; v[3] *= v[3]; }
        short4 pk; pk.x = f2bf(v[0]); pk.y = f2bf(v[1]); pk.z = f2bf(v[2]); pk.w = f2bf(v[3]);
        *(short4*)&T[ml * 132 + wn + nt * 16 + q * 4] = pk;
      }
    }
    __syncthreads();
#pragma unroll
    for (int t2 = 0; t2 < 2; ++t2) {
      int task = tid + t2 * 256;
      int row = task & 127, hl = task >> 7;
      size_t obase = ((size_t)((n0 >> 5) + hl) * NROWS + m0 + row) * 32;
#pragma unroll
      for (int j = 0; j < 4; ++j)
        *(bf16x8*)&outz[obase + j * 8] = *(const bf16x8*)&T[row * 132 + hl * 32 + j * 8];
    }
  } else if (EPI == 1) {
#pragma unroll
    for (int mt = 0; mt < 4; ++mt) {
      int ml = wm + mt * 16 + r;
#pragma unroll
      for (int nt = 0; nt < 4; ++nt) {
        f32x4 v = acc[mt][nt];
        v[0] += bias4[nt].x; v[1] += bias4[nt].y; v[2] += bias4[nt].z; v[3] += bias4[nt].w;
#pragma unroll
        for (int e = 0; e < 4; ++e) v[e] = fast_gelu(v[e]);
        short4 o; o.x = f2bf(v[0]); o.y = f2bf(v[1]); o.z = f2bf(v[2]); o.w = f2bf(v[3]);
        int n = n0 + wn + nt * 16 + q * 4;
        size_t ti = ((size_t)blockIdx.x * (N >> 5) + (n >> 5)) * 4096 +
                    (size_t)(((n >> 3) & 3) << 10) + (ml << 3) + (n & 7);
        *(short4*)&outz[ti] = o;
      }
    }
  } else {
    // h += acc + bias, staged via LDS [128][68] f32, two 64-n rounds
    float* TF = (float*)L;
#pragma unroll
    for (int half = 0; half < 2; ++half) {
      __syncthreads();
      if ((w & 1) == half) {
#pragma unroll
        for (int mt = 0; mt < 4; ++mt) {
          int ml = wm + mt * 16 + r;
#pragma unroll
          for (int nt = 0; nt < 4; ++nt) {
            f32x4 v = acc[mt][nt];
            v[0] += bias4[nt].x; v[1] += bias4[nt].y; v[2] += bias4[nt].z; v[3] += bias4[nt].w;
            *(f32x4*)&TF[ml * 68 + nt * 16 + q * 4] = v;
          }
        }
      }
      __syncthreads();
      int row = tid >> 1, col = (tid & 1) * 32;
      size_t hoff = (size_t)(m0 + row) * N + n0 + half * 64 + col;
#pragma unroll
      for (int j = 0; j < 8; ++j) {
        float4 add = *(const float4*)&TF[row * 68 + col + j * 4];
        float4 cur4 = *(float4*)&outf[hoff + j * 4];
        cur4.x += add.x; cur4.y += add.y; cur4.z += add.z; cur4.w += add.w;
        *(float4*)&outf[hoff + j * 4] = cur4;
      }
    }
  }
}

// ---------------- fused FFN: h += gelu(hn@WU+bU)@WV + bV ---------------------
// R17 structure (1 block/CU, 512 thr, 32 steps, 2x32KB slots, 160KB LDS,
// clean full-row epilogue) + T5 setprio around the compute phase of each step.
__global__ __launch_bounds__(512) void ffn_fused(
    const short* __restrict__ A, const short* __restrict__ TUw,
    const short* __restrict__ TVw, const float* __restrict__ bUp,
    const float* __restrict__ bVp, float* __restrict__ h) {
  __shared__ __align__(16) short L[81920];  // 160KB exactly
  int tid = threadIdx.x;
  int lane = tid & 63, w = tid >> 6;
  int q = lane >> 4, r = lane & 15;
  int wmU = (w >> 2) * 64, wnU = (w & 3) * 32;   // up: wave = 64 rows x 32 f
  int wmD = (w >> 2) * 64, wnD = (w & 3) * 64;   // down: wave = 64 rows x 64 d
  const short* At = A + (size_t)blockIdx.x * 32768;

  // A strip -> LDS: 64KB contiguous tiled layout, 8 gld16/thread (oldest vmem)
#pragma unroll
  for (int i = 0; i < 8; ++i)
    gld16(At + (i * 512 + tid) * 8, &L[(i * 512 + tid) * 8]);

  auto issueFor = [&](int t) {  // stage 32KB slot(t) into buf[t&1]; 4 gld16/thread
    short* dst = &L[49152 + (t & 1) * 16384];
    int ss = t >> 2, pp = t & 3;
    if (pp < 2) {  // up: WU tiles ss*8 + pp*4 .. +3 (contiguous 32KB)
      const short* g0 = TUw + ((size_t)ss * 8 + pp * 4) * 4096;
#pragma unroll
      for (int i = 0; i < 4; ++i)
        gld16(g0 + (i * 512 + tid) * 8, dst + (i * 512 + tid) * 8);
    } else {       // down: kbg pair; per kbg: WV tiles (kbg) and (32+kbg)
      int kbg0 = ss * 4 + (pp - 2) * 2;
#pragma unroll
      for (int kl = 0; kl < 2; ++kl) {
        gld16(TVw + (size_t)(kbg0 + kl) * 4096 + tid * 8,
              dst + kl * 8192 + tid * 8);
        gld16(TVw + (size_t)(32 + kbg0 + kl) * 4096 + tid * 8,
              dst + kl * 8192 + 4096 + tid * 8);
      }
    }
  };

  issueFor(0); issueFor(1);

  f32x4 vzero = {0.f, 0.f, 0.f, 0.f};
  f32x4 accm[4][2], acco[4][4];
#pragma unroll
  for (int mt = 0; mt < 4; ++mt) {
#pragma unroll
    for (int nt = 0; nt < 2; ++nt) accm[mt][nt] = vzero;
#pragma unroll
    for (int nt = 0; nt < 4; ++nt) acco[mt][nt] = vzero;
  }
  float4 b4[2];

  auto slice = [&](int s, auto lastc) {
    constexpr bool LAST = decltype(lastc)::value;
    // ---- up steps p=0,1: slot(s*4+p) holds WU kb = 4p..4p+3 ----
#pragma unroll
    for (int p = 0; p < 2; ++p) {
      int sig = s * 4 + p;
      __builtin_amdgcn_s_waitcnt(0x0f74);  // vmcnt(4)
      __builtin_amdgcn_s_barrier();
      __builtin_amdgcn_s_setprio(1);
      const short* Ws = &L[49152 + (sig & 1) * 16384];
#pragma unroll
      for (int kl = 0; kl < 4; ++kl) {
        int kb = p * 4 + kl;
        bf16x8 af[4], bfr[2];
#pragma unroll
        for (int mt = 0; mt < 4; ++mt)
          af[mt] = *(const bf16x8*)&L[kb * 4096 + (q * 128 + wmU + mt * 16 + r) * 8];
#pragma unroll
        for (int nt = 0; nt < 2; ++nt)
          bfr[nt] = *(const bf16x8*)&Ws[kl * 4096 + (q * 128 + wnU + nt * 16 + r) * 8];
#pragma unroll
        for (int mt = 0; mt < 4; ++mt)
#pragma unroll
          for (int nt = 0; nt < 2; ++nt)
            accm[mt][nt] = __builtin_amdgcn_mfma_f32_16x16x32_bf16(
                bfr[nt], af[mt], accm[mt][nt], 0, 0, 0);
      }
      __builtin_amdgcn_s_setprio(0);
      if (p == 1) {  // slice's K done: bias + gelu + pack -> mid (A-tile fmt)
#pragma unroll
        for (int mt = 0; mt < 4; ++mt) {
          int row = wmU + mt * 16 + r;
#pragma unroll
          for (int nt = 0; nt < 2; ++nt) {
            f32x4 v = accm[mt][nt];
            float4 bb = b4[nt];
            v[0] += bb.x; v[1] += bb.y; v[2] += bb.z; v[3] += bb.w;
            short4 pk;
            pk.x = f2bf(fast_gelu(v[0])); pk.y = f2bf(fast_gelu(v[1]));
            pk.z = f2bf(fast_gelu(v[2])); pk.w = f2bf(fast_gelu(v[3]));
            int kc8 = 2 * nt + (q >> 1);  // f = wnU + nt*16 + q*4 + e
            *(short4*)&L[32768 + (w & 3) * 4096 + (kc8 * 128 + row) * 8 + (q & 1) * 4] = pk;
            accm[mt][nt] = vzero;
          }
        }
      }
      __builtin_amdgcn_s_waitcnt(0xc07f);  // lgkmcnt(0)
      __builtin_amdgcn_s_barrier();
      if (p == 0) {  // bU for this slice BEFORE the issue: next vmcnt(4)
                     // drains [slot sig+1 (4) + b4 (2)], leaving slot sig+2.
        b4[0] = *(const float4*)&bUp[s * 128 + wnU + q * 4];
        b4[1] = *(const float4*)&bUp[s * 128 + wnU + 16 + q * 4];
      }
      if (sig + 2 < 32) issueFor(sig + 2);
    }
    // ---- down steps p2=0,1: slot(s*4+2+p2) = kbg pair ----
#pragma unroll
    for (int p2 = 0; p2 < 2; ++p2) {
      int sig = s * 4 + 2 + p2;
      if (LAST && p2 == 1) __builtin_amdgcn_s_waitcnt(0x0f70);  // vmcnt(0)
      else                 __builtin_amdgcn_s_waitcnt(0x0f74);  // vmcnt(4)
      __builtin_amdgcn_s_barrier();
      __builtin_amdgcn_s_setprio(1);
      const short* Ws = &L[49152 + (sig & 1) * 16384];
#pragma unroll
      for (int kl = 0; kl < 2; ++kl) {
        int mtile = p2 * 2 + kl;  // mid tile (f-block) 0..3
        bf16x8 am[4], bvf[4];
#pragma unroll
        for (int mt = 0; mt < 4; ++mt)
          am[mt] = *(const bf16x8*)&L[32768 + mtile * 4096 + (q * 128 + wmD + mt * 16 + r) * 8];
#pragma unroll
        for (int nt = 0; nt < 4; ++nt)
          bvf[nt] = *(const bf16x8*)&Ws[kl * 8192 + (wnD >> 7) * 4096 +
                                        (q * 128 + (wnD & 127) + nt * 16 + r) * 8];
#pragma unroll
        for (int mt = 0; mt < 4; ++mt)
#pragma unroll
          for (int nt = 0; nt < 4; ++nt)
            acco[mt][nt] = __builtin_amdgcn_mfma_f32_16x16x32_bf16(
                bvf[nt], am[mt], acco[mt][nt], 0, 0, 0);
      }
      __builtin_amdgcn_s_setprio(0);
      __builtin_amdgcn_s_waitcnt(0xc07f);  // lgkmcnt(0)
      __builtin_amdgcn_s_barrier();
      if (sig + 2 < 32) issueFor(sig + 2);
    }
  };

  for (int s = 0; s < 7; ++s) slice(s, FalseT{});
  slice(7, TrueT{});

  // epilogue (R11): out += bV; stage [128][260] f32 in LDS; FULL-ROW h RMW
  float4 bv4[4];
#pragma unroll
  for (int nt = 0; nt < 4; ++nt) bv4[nt] = *(const float4*)&bVp[wnD + nt * 16 + q * 4];
  float* TF = (float*)L;
#pragma unroll
  for (int mt = 0; mt < 4; ++mt) {
    int row = wmD + mt * 16 + r;
#pragma unroll
    for (int nt = 0; nt < 4; ++nt) {
      f32x4 v = acco[mt][nt];
      v[0] += bv4[nt].x; v[1] += bv4[nt].y; v[2] += bv4[nt].z; v[3] += bv4[nt].w;
      *(f32x4*)&TF[row * 260 + wnD + nt * 16 + q * 4] = v;
    }
  }
  __syncthreads();
  size_t hbase = ((size_t)blockIdx.x * 128 + w * 16) * DD;
#pragma unroll
  for (int j = 0; j < 16; ++j) {
    float4 add = *(const float4*)&TF[(w * 16 + j) * 260 + lane * 4];
    float4 c4 = *(float4*)&h[hbase + (size_t)j * DD + lane * 4];
    c4.x += add.x; c4.y += add.y; c4.z += add.z; c4.w += add.w;
    *(float4*)&h[hbase + (size_t)j * DD + lane * 4] = c4;
  }
}

// ---------------- attention A1: per (b,h,chunk) S_c = K^T V, z_c = sum k ------
// q/k/v head-major: [head][32768][32]
__global__ __launch_bounds__(256) void attn_chunk_kv(
    const short* __restrict__ Kb, const short* __restrict__ Vb,
    float* __restrict__ St, float* __restrict__ Zc) {
  __shared__ short Kt[4][32 * 72];
  __shared__ short Vt[4][32 * 72];
  int wid = threadIdx.x >> 6;
  int blk = blockIdx.x * 4 + wid;
  int c = blk & (NC - 1), bh = blk >> 5;
  int b = bh >> 3, hh = bh & 7;
  int lane = threadIdx.x & 63, q = lane >> 4, r = lane & 15;
  size_t rowbase = ((size_t)hh * NROWS + b * GG + c * CS + lane) * 32;
#pragma unroll
  for (int j = 0; j < 4; ++j) {
    bf16x8 kv = *(const bf16x8*)&Kb[rowbase + j * 8];
    bf16x8 vv = *(const bf16x8*)&Vb[rowbase + j * 8];
#pragma unroll
    for (int e = 0; e < 8; ++e) {
      Kt[wid][(j * 8 + e) * 72 + lane] = kv[e];
      Vt[wid][(j * 8 + e) * 72 + lane] = vv[e];
    }
  }
  __syncthreads();
  f32x4 vzero = {0.f, 0.f, 0.f, 0.f};
  f32x4 acc[2][2];
#pragma unroll
  for (int i = 0; i < 2; ++i)
#pragma unroll
    for (int j = 0; j < 2; ++j) acc[i][j] = vzero;
#pragma unroll
  for (int ks = 0; ks < 2; ++ks) {
    bf16x8 afr[2], bfr[2];
#pragma unroll
    for (int mt = 0; mt < 2; ++mt) afr[mt] = *(const bf16x8*)&Kt[wid][(mt * 16 + r) * 72 + ks * 32 + q * 8];
#pragma unroll
    for (int nt = 0; nt < 2; ++nt) bfr[nt] = *(const bf16x8*)&Vt[wid][(nt * 16 + r) * 72 + ks * 32 + q * 8];
#pragma unroll
    for (int mt = 0; mt < 2; ++mt)
#pragma unroll
      for (int nt = 0; nt < 2; ++nt)
        acc[mt][nt] = __builtin_amdgcn_mfma_f32_16x16x32_bf16(afr[mt], bfr[nt], acc[mt][nt], 0, 0, 0);
  }
  float* stp = St + ((size_t)bh * NC + c) * 1024;
#pragma unroll
  for (int mt = 0; mt < 2; ++mt)
#pragma unroll
    for (int nt = 0; nt < 2; ++nt)
      *(f32x4*)&stp[(nt * 16 + r) * 32 + mt * 16 + q * 4] = acc[mt][nt];  // St[d][f]
  if (lane < 32) {
    float s = 0.f;
#pragma unroll
    for (int j = 0; j < 8; ++j) {
      bf16x8 kr = *(const bf16x8*)&Kt[wid][lane * 72 + j * 8];
#pragma unroll
      for (int e = 0; e < 8; ++e) s += bf2f(kr[e]);
    }
    Zc[((size_t)bh * NC + c) * 32 + lane] = s;
  }
}

// ---------------- attention A2: exclusive prefix over chunks ------------------
__global__ __launch_bounds__(1024) void attn_prefix(float* __restrict__ St, float* __restrict__ Zc) {
  int bh = blockIdx.x, i = threadIdx.x;
  float run = 0.f;
  float* p = St + (size_t)bh * NC * 1024 + i;
#pragma unroll
  for (int c = 0; c < NC; ++c) { float t = p[(size_t)c * 1024]; p[(size_t)c * 1024] = run; run += t; }
  if (i < 32) {
    float rz = 0.f;
    float* pz = Zc + (size_t)bh * NC * 32 + i;
#pragma unroll
    for (int c = 0; c < NC; ++c) { float t = pz[c * 32]; pz[c * 32] = rz; rz += t; }
  }
}

// ---------------- attention B: intra-chunk + apply, h += out ------------------
// Block = (b, c, hg): 4 waves handle 4 ADJACENT heads hh = hg*4+wid of the
// SAME 64-row chunk. Epilogue: O*inv staged to LDS (reuse dead P region),
// then coalesced 512B half-row float4 RMW of h (full cache lines).
__global__ __launch_bounds__(256) void attn_intra(
    const short* __restrict__ Qb, const short* __restrict__ Kb,
    const short* __restrict__ Vb, const float* __restrict__ St,
    const float* __restrict__ Zc, float* __restrict__ h) {
  __shared__ __align__(16) short P[4][64 * 72];
  __shared__ short Vt[4][32 * 72];
  __shared__ float den[4][64];
  int wid = threadIdx.x >> 6;
  int u = blockIdx.x;
  int b = u >> 6, c = (u >> 1) & (NC - 1), hg = u & 1;
  int hh = hg * 4 + wid;
  int bh = b * 8 + hh;
  int lane = threadIdx.x & 63, q = lane >> 4, r = lane & 15;
  size_t hrow0 = (size_t)b * GG + c * CS;                 // rows in h (row-major)
  size_t qrow0 = (size_t)hh * NROWS + b * GG + c * CS;    // rows in head-major qkv

  const float* zp = Zc + ((size_t)bh * NC + c) * 32;
  float qz = 0.f;
  {
    size_t qoff = (qrow0 + lane) * 32;
#pragma unroll
    for (int j = 0; j < 4; ++j) {
      bf16x8 qv = *(const bf16x8*)&Qb[qoff + j * 8];
#pragma unroll
      for (int e = 0; e < 8; ++e) qz += bf2f(qv[e]) * zp[j * 8 + e];
    }
  }
  den[wid][lane] = qz;

  {
    size_t voff = (qrow0 + lane) * 32;
#pragma unroll
    for (int j = 0; j < 4; ++j) {
      bf16x8 vv = *(const bf16x8*)&Vb[voff + j * 8];
#pragma unroll
      for (int e = 0; e < 8; ++e) Vt[wid][(j * 8 + e) * 72 + lane] = vv[e];
    }
  }

  bf16x8 ak[4], bqf[4];
#pragma unroll
  for (int t4 = 0; t4 < 4; ++t4) {
    ak[t4]  = *(const bf16x8*)&Kb[(qrow0 + t4 * 16 + r) * 32 + q * 8];
    bqf[t4] = *(const bf16x8*)&Qb[(qrow0 + t4 * 16 + r) * 32 + q * 8];
  }
  f32x4 vzero = {0.f, 0.f, 0.f, 0.f};
  f32x4 pacc[4][4];
#pragma unroll
  for (int mt = 0; mt < 4; ++mt)
#pragma unroll
    for (int nt = 0; nt < 4; ++nt)
      pacc[mt][nt] = __builtin_amdgcn_mfma_f32_16x16x32_bf16(ak[mt], bqf[nt], vzero, 0, 0, 0);

  float rs[4] = {0.f, 0.f, 0.f, 0.f};
#pragma unroll
  for (int nt = 0; nt < 4; ++nt) {
    int t = nt * 16 + r;
#pragma unroll
    for (int mt = 0; mt < 4; ++mt) {
      short4 pk;
#pragma unroll
      for (int rr = 0; rr < 4; ++rr) {
        int s = mt * 16 + q * 4 + rr;
        float pv = (s <= t) ? pacc[mt][nt][rr] : 0.f;
        rs[nt] += pv;
        ((short*)&pk)[rr] = f2bf(pv);
      }
      *(short4*)&P[wid][t * 72 + mt * 16 + q * 4] = pk;
    }
  }
#pragma unroll
  for (int nt = 0; nt < 4; ++nt) {
    rs[nt] += __shfl_xor(rs[nt], 16);
    rs[nt] += __shfl_xor(rs[nt], 32);
  }
  __syncthreads();
  if (lane < 16) {
#pragma unroll
    for (int nt = 0; nt < 4; ++nt) den[wid][nt * 16 + lane] += rs[nt];
  }
  __syncthreads();

  f32x4 oacc[4][2];
#pragma unroll
  for (int mt = 0; mt < 4; ++mt)
#pragma unroll
    for (int nt2 = 0; nt2 < 2; ++nt2) oacc[mt][nt2] = vzero;
  const float* stp = St + ((size_t)bh * NC + c) * 1024;
#pragma unroll
  for (int nt2 = 0; nt2 < 2; ++nt2) {
    float4 s0 = *(const float4*)&stp[(nt2 * 16 + r) * 32 + q * 8];
    float4 s1 = *(const float4*)&stp[(nt2 * 16 + r) * 32 + q * 8 + 4];
    bf16x8 bs;
    bs[0] = f2bf(s0.x); bs[1] = f2bf(s0.y); bs[2] = f2bf(s0.z); bs[3] = f2bf(s0.w);
    bs[4] = f2bf(s1.x); bs[5] = f2bf(s1.y); bs[6] = f2bf(s1.z); bs[7] = f2bf(s1.w);
#pragma unroll
    for (int mt = 0; mt < 4; ++mt)
      oacc[mt][nt2] = __builtin_amdgcn_mfma_f32_16x16x32_bf16(bqf[mt], bs, oacc[mt][nt2], 0, 0, 0);
  }
#pragma unroll
  for (int ks = 0; ks < 2; ++ks) {
    bf16x8 ap[4];
#pragma unroll
    for (int mt = 0; mt < 4; ++mt)
      ap[mt] = *(const bf16x8*)&P[wid][(mt * 16 + r) * 72 + ks * 32 + q * 8];
#pragma unroll
    for (int nt2 = 0; nt2 < 2; ++nt2) {
      bf16x8 bv_ = *(const bf16x8*)&Vt[wid][(nt2 * 16 + r) * 72 + ks * 32 + q * 8];
#pragma unroll
      for (int mt = 0; mt < 4; ++mt)
        oacc[mt][nt2] = __builtin_amdgcn_mfma_f32_16x16x32_bf16(ap[mt], bv_, oacc[mt][nt2], 0, 0, 0);
    }
  }

  // ---- epilogue: stage O*inv -> LDS (P region is dead), coalesced h RMW ----
  float* OF = (float*)&P[0][0];  // [64][132] f32 = 33.8KB (P region = 36.9KB)
  __syncthreads();               // all waves done reading P
#pragma unroll
  for (int mt = 0; mt < 4; ++mt) {
#pragma unroll
    for (int rr = 0; rr < 4; ++rr) {
      int t = mt * 16 + q * 4 + rr;
      float inv = 1.0f / (den[wid][t] + 1e-16f);
#pragma unroll
      for (int nt2 = 0; nt2 < 2; ++nt2)
        OF[t * 132 + wid * 32 + nt2 * 16 + r] = oacc[mt][nt2][rr] * inv;
    }
  }
  __syncthreads();
  int tid = threadIdx.x;
#pragma unroll
  for (int p = 0; p < 8; ++p) {
    int row = p * 8 + (tid >> 5);
    int f4 = (tid & 31) * 4;
    size_t off = (hrow0 + row) * DD + hg * 128 + f4;
    float4 cv = *(float4*)&h[off];
    float4 ad = *(const float4*)&OF[row * 132 + f4];
    cv.x += ad.x; cv.y += ad.y; cv.z += ad.z; cv.w += ad.w;
    *(float4*)&h[off] = cv;
  }
}

// ---------------- final projection -------------------------------------------
__global__ __launch_bounds__(256) void out_proj(
    const float* __restrict__ h, const float* __restrict__ Wout,
    const float* __restrict__ bout, float* __restrict__ out) {
  int row = blockIdx.x * 4 + (threadIdx.x >> 6);
  int lane = threadIdx.x & 63;
  float4 a = *(const float4*)&h[(size_t)row * DD + lane * 4];
  float4 w = *(const float4*)&Wout[lane * 4];
  float s = a.x * w.x + a.y * w.y + a.z * w.z + a.w * w.w;
#pragma unroll
  for (int o = 1; o < 64; o <<= 1) s += __shfl_xor(s, o);
  if (lane == 0) out[row] = s + bout[0];
}

extern "C" void kernel_launch(void* const* d_in, const int* in_sizes, int n_in,
                              void* d_out, int out_size, void* d_ws, size_t ws_size,
                              hipStream_t stream) {
  const float* x    = (const float*)d_in[0];
  const float* ge   = (const float*)d_in[1];
  const float* invf = (const float*)d_in[2];
  const float* Wq   = (const float*)d_in[3];
  const float* bq   = (const float*)d_in[4];
  const float* Wk   = (const float*)d_in[5];
  const float* bk   = (const float*)d_in[6];
  const float* Wv   = (const float*)d_in[7];
  const float* bv   = (const float*)d_in[8];
  const float* ln1g = (const float*)d_in[9];
  const float* ln1b = (const float*)d_in[10];
  const float* ln2g = (const float*)d_in[11];
  const float* ln2b = (const float*)d_in[12];
  const float* WU   = (const float*)d_in[13];
  const float* bU   = (const float*)d_in[14];
  const float* WV   = (const float*)d_in[15];
  const float* bV   = (const float*)d_in[16];
  const float* Wout = (const float*)d_in[17];
  const float* bout = (const float*)d_in[18];
  float* out = (float*)d_out;

  char* ws = (char*)d_ws;
  float* h   = (float*)(ws + 0);            // 33.5 MB
  short* hn  = (short*)(ws + 33554432);     // 16.8 MB (tiled)
  char*  R   = ws + 50331648;               // shared region
  short* qb  = (short*)(R + 0);             // head-major [8][32768][32]
  short* kb  = (short*)(R + 16777216);
  short* vb  = (short*)(R + 33554432);
  float* St  = (float*)(R + 50331648);
  float* Zc  = (float*)(R + 67108864);
  char*  WT  = R + 67633152;
  short* TQ  = (short*)(WT + 0);
  short* TK  = (short*)(WT + 524288);
  short* TVq = (short*)(WT + 1048576);
  short* TU  = (short*)(WT + 1572864);
  short* TVd = (short*)(WT + 3670016);

  prep_weights<<<dim3(1024, 4, 5), 256, 0, stream>>>(Wq, Wk, Wv, WU, WV, TQ, TK, TVq, TU, TVd);
  embed_kernel<<<NROWS / 4, 256, 0, stream>>>(x, ge, invf, h);

  for (int l = 0; l < 4; ++l) {
    ln_tiled<<<NROWS / 32, 256, 0, stream>>>(h, ln1g + l * 256, ln1b + l * 256, hn);
    gemm_t<256, 0><<<dim3(256, 2, 3), 256, 0, stream>>>(
        hn, TQ + l * 65536, TK + l * 65536, TVq + l * 65536,
        bq + l * 256, bk + l * 256, bv + l * 256,
        qb, kb, vb, nullptr, 256);
    attn_chunk_kv<<<1024, 256, 0, stream>>>(kb, vb, St, Zc);
    attn_prefix<<<128, 1024, 0, stream>>>(St, Zc);
    attn_intra<<<1024, 256, 0, stream>>>(qb, kb, vb, St, Zc, h);
    ln_tiled<<<NROWS / 32, 256, 0, stream>>>(h, ln2g + l * 256, ln2b + l * 256, hn);
    ffn_fused<<<256, 512, 0, stream>>>(hn, TU + l * 262144, TVd + l * 262144,
                                       bU + l * 1024, bV + l * 256, h);
  }
  out_proj<<<NROWS / 4, 256, 0, stream>>>(h, Wout, bout, out);
}

// Round 10
// 710.126 us; speedup vs baseline: 1.1091x; 1.0607x over previous
//
#include <hip/hip_runtime.h>
#include <math.h>

// ExpressionPerformer: B=16,G=2048,D=256,H=8,dh=32,FFN=1024,L=4
// Round-19: LayerNorm FUSION into producer epilogues (kill 7 of 8 ln_tiled).
//  - ffn_fused epilogue: h-RMW restructured so wave w owns rows {p*8+w} with
//    full 1KB-contiguous per-instruction access; computes LN1[l+1] stats via
//    wave shuffle reduce during the RMW, then writes tiled hn directly from
//    TF (h_new staged back into LDS). ln1g==nullptr on last layer skips it.
//    TF stride 260->268. T5 setprio REMOVED from ffn (R18: +2.8us regression).
//  - attn_intra: 8 waves = all 8 heads of one (b,c) 64-row chunk (512 thr,
//    113KB LDS, same 8 waves/CU). Epilogue holds full 256-col rows -> fused
//    LN2 + tiled hn write, same wave-owns-row RMW pattern.
//  - ln_tiled survives only for layer-0 LN1 (after embed).
//  - gemm_t keeps setprio (bundled with R18's +14us; low risk).

#define GG 2048
#define DD 256
#define NROWS 32768
#define NC 32
#define CS 64

typedef __attribute__((ext_vector_type(8))) short bf16x8;
typedef __attribute__((ext_vector_type(4))) float f32x4;

struct FalseT { static constexpr bool value = false; };
struct TrueT  { static constexpr bool value = true;  };

__device__ __forceinline__ short f2bf(float f) {
  union { float f; unsigned u; } v; v.f = f;
  unsigned r = v.u + 0x7FFFu + ((v.u >> 16) & 1u);
  return (short)(r >> 16);
}
__device__ __forceinline__ float bf2f(short s) {
  union { unsigned u; float f; } v; v.u = ((unsigned)(unsigned short)s) << 16;
  return v.f;
}
__device__ __forceinline__ void gld16(const short* g, short* l) {
  __builtin_amdgcn_global_load_lds(
      (const __attribute__((address_space(1))) void*)g,
      (__attribute__((address_space(3))) void*)l, 16, 0, 0);
}
__device__ __forceinline__ float fast_gelu(float x) {
  float y = 1.595769122f * (x + 0.044715f * x * x * x);
  return x / (1.0f + __expf(-y));
}

// ---------------- embed ------------------------------------------------------
__global__ __launch_bounds__(256) void embed_kernel(
    const float* __restrict__ x, const float* __restrict__ ge,
    const float* __restrict__ invf, float* __restrict__ h) {
  int bg = blockIdx.x * 4 + (threadIdx.x >> 6);
  int g = bg & (GG - 1);
  int lane = threadIdx.x & 63;
  float xv = x[bg];
  int d = lane * 4;
  float4 e;
  if (lane < 32) {
    float4 f = *(const float4*)&invf[d];
    e.x = sinf(xv * f.x); e.y = sinf(xv * f.y);
    e.z = sinf(xv * f.z); e.w = sinf(xv * f.w);
  } else {
    float4 f = *(const float4*)&invf[d - 128];
    e.x = cosf(xv * f.x); e.y = cosf(xv * f.y);
    e.z = cosf(xv * f.z); e.w = cosf(xv * f.w);
  }
  if (xv == -10.0f) { e.x = 0.f; e.y = 0.f; e.z = 0.f; e.w = 0.f; }
  float4 gv = *(const float4*)&ge[(size_t)g * DD + d];
  float4 o; o.x = gv.x + e.x; o.y = gv.y + e.y; o.z = gv.z + e.z; o.w = gv.w + e.w;
  *(float4*)&h[(size_t)bg * DD + d] = o;
}

// ---------------- layernorm -> TILED bf16 (layer-0 LN1 only) -----------------
__global__ __launch_bounds__(256) void ln_tiled(
    const float* __restrict__ h, const float* __restrict__ gamma,
    const float* __restrict__ beta, short* __restrict__ outT) {
  __shared__ float mean_s[32], rstd_s[32];
  __shared__ float gls[256], bls[256];
  int r0 = blockIdx.x * 32;
  int tid = threadIdx.x;
  gls[tid] = gamma[tid]; bls[tid] = beta[tid];
  {
    int row = tid >> 3, seg = tid & 7;
    const float4* hp = (const float4*)(h + (size_t)(r0 + row) * DD + seg * 32);
    float s = 0.f, s2 = 0.f;
#pragma unroll
    for (int i = 0; i < 8; ++i) {
      float4 v = hp[i];
      s += v.x + v.y + v.z + v.w;
      s2 += v.x * v.x + v.y * v.y + v.z * v.z + v.w * v.w;
    }
    s += __shfl_xor(s, 1); s += __shfl_xor(s, 2); s += __shfl_xor(s, 4);
    s2 += __shfl_xor(s2, 1); s2 += __shfl_xor(s2, 2); s2 += __shfl_xor(s2, 4);
    if (seg == 0) {
      float mn = s * (1.0f / 256.0f);
      mean_s[row] = mn;
      rstd_s[row] = rsqrtf(s2 * (1.0f / 256.0f) - mn * mn + 1e-5f);
    }
  }
  __syncthreads();
  int row = tid & 31, kc8 = (tid >> 5) & 3, half = tid >> 7;
  float mn = mean_s[row], rs = rstd_s[row];
  size_t hrow = (size_t)(r0 + row) * DD;
  int trow = (r0 & 127) + row;
  short* tb = outT + (size_t)(r0 >> 7) * 8 * 4096 + (kc8 * 128 + trow) * 8;
#pragma unroll
  for (int j = 0; j < 4; ++j) {
    int kb = half * 4 + j;
    int k0 = kb * 32 + kc8 * 8;
    float4 x0 = *(const float4*)&h[hrow + k0];
    float4 x1 = *(const float4*)&h[hrow + k0 + 4];
    float4 g0 = *(const float4*)&gls[k0], g1 = *(const float4*)&gls[k0 + 4];
    float4 b0 = *(const float4*)&bls[k0], b1 = *(const float4*)&bls[k0 + 4];
    bf16x8 aw;
    aw[0] = f2bf((x0.x - mn) * rs * g0.x + b0.x);
    aw[1] = f2bf((x0.y - mn) * rs * g0.y + b0.y);
    aw[2] = f2bf((x0.z - mn) * rs * g0.z + b0.z);
    aw[3] = f2bf((x0.w - mn) * rs * g0.w + b0.w);
    aw[4] = f2bf((x1.x - mn) * rs * g1.x + b1.x);
    aw[5] = f2bf((x1.y - mn) * rs * g1.y + b1.y);
    aw[6] = f2bf((x1.z - mn) * rs * g1.z + b1.z);
    aw[7] = f2bf((x1.w - mn) * rs * g1.w + b1.w);
    *(bf16x8*)&tb[(size_t)kb * 4096] = aw;
  }
}

// ---------------- weight convert+transpose -> TILED --------------------------
__global__ __launch_bounds__(256) void prep_weights(
    const float* __restrict__ Wq, const float* __restrict__ Wk,
    const float* __restrict__ Wv, const float* __restrict__ WU,
    const float* __restrict__ WV,
    short* __restrict__ TQ, short* __restrict__ TK, short* __restrict__ TV,
    short* __restrict__ TU, short* __restrict__ TVd) {
  int zz = blockIdx.z, l = blockIdx.y;
  const float* src; short* dst; int Kd, Nd;
  if (zz == 0) { src = Wq; dst = TQ; Kd = 256; Nd = 256; }
  else if (zz == 1) { src = Wk; dst = TK; Kd = 256; Nd = 256; }
  else if (zz == 2) { src = Wv; dst = TV; Kd = 256; Nd = 256; }
  else if (zz == 3) { src = WU; dst = TU; Kd = 256; Nd = 1024; }
  else { src = WV; dst = TVd; Kd = 1024; Nd = 256; }
  int tot = Kd * Nd;
  int e = blockIdx.x * 256 + threadIdx.x;
  if (e >= tot) return;
  int t = e >> 12;
  int cslot = (e >> 3) & 511;
  int elem = e & 7;
  int kc8 = cslot >> 7, rn = cslot & 127;
  int nKb = Kd >> 5;
  int nt = t / nKb, kb = t - nt * nKb;
  int n = nt * 128 + rn, k = kb * 32 + kc8 * 8 + elem;
  dst[(size_t)l * tot + e] = f2bf(src[(size_t)l * tot + (size_t)k * Nd + n]);
}

// ---------------- bf16 MFMA GEMM (tiled operands, compile-time K) -------------
template <int K, int EPI>
__global__ __launch_bounds__(256) void gemm_t(
    const short* __restrict__ A, const short* __restrict__ B0,
    const short* __restrict__ B1, const short* __restrict__ B2,
    const float* __restrict__ bias0, const float* __restrict__ bias1,
    const float* __restrict__ bias2,
    short* __restrict__ o0, short* __restrict__ o1, short* __restrict__ o2,
    float* __restrict__ outf, int N) {
  __shared__ __align__(16) short L[24576];  // 48KB
  constexpr int nIter = K / 32;
  int z = blockIdx.z;
  const short* Bt = (z == 0) ? B0 : (z == 1) ? B1 : B2;
  const float* bias = (z == 0) ? bias0 : (z == 1) ? bias1 : bias2;
  short* outz = (z == 0) ? o0 : (z == 1) ? o1 : o2;
  int m0 = blockIdx.x * 128, n0 = blockIdx.y * 128;
  int tid = threadIdx.x;
  int lane = tid & 63, w = tid >> 6;
  int q = lane >> 4, r = lane & 15;
  int wm = (w >> 1) * 64, wn = (w & 1) * 64;
  const short* At = A + (size_t)blockIdx.x * nIter * 4096;
  const short* Btl = Bt + (size_t)blockIdx.y * nIter * 4096;
  f32x4 vzero = {0.f, 0.f, 0.f, 0.f};
  f32x4 acc[4][4];
#pragma unroll
  for (int i = 0; i < 4; ++i)
#pragma unroll
    for (int j = 0; j < 4; ++j) acc[i][j] = vzero;

  int c0 = tid * 8, c1 = (tid + 256) * 8;
#pragma unroll
  for (int g = 0; g < 3; ++g) {
    gld16(At + g * 4096 + c0, &L[g * 4096 + c0]);
    gld16(At + g * 4096 + c1, &L[g * 4096 + c1]);
    gld16(Btl + g * 4096 + c0, &L[12288 + g * 4096 + c0]);
    gld16(Btl + g * 4096 + c1, &L[12288 + g * 4096 + c1]);
  }

  int abase = (q * 128 + wm + r) * 8;
  int bbase = (q * 128 + wn + r) * 8;

#pragma unroll
  for (int gi = 0; gi < nIter; ++gi) {
    const int rem = nIter - 1 - gi;
    if (rem >= 2)      __builtin_amdgcn_s_waitcnt(0x0f78);  // vmcnt(8)
    else if (rem == 1) __builtin_amdgcn_s_waitcnt(0x0f74);  // vmcnt(4)
    else               __builtin_amdgcn_s_waitcnt(0x0f70);  // vmcnt(0)
    __builtin_amdgcn_s_barrier();
    __builtin_amdgcn_s_setprio(1);
    const int cur = gi % 3;
    const short* Asc = &L[cur * 4096];
    const short* Bsc = &L[12288 + cur * 4096];
    bf16x8 af[4], bfr[4];
#pragma unroll
    for (int mt = 0; mt < 4; ++mt)
      af[mt] = *(const bf16x8*)&Asc[abase + mt * 16 * 8];
#pragma unroll
    for (int nt = 0; nt < 4; ++nt)
      bfr[nt] = *(const bf16x8*)&Bsc[bbase + nt * 16 * 8];
#pragma unroll
    for (int mt = 0; mt < 4; ++mt)
#pragma unroll
      for (int nt = 0; nt < 4; ++nt)
        acc[mt][nt] = __builtin_amdgcn_mfma_f32_16x16x32_bf16(bfr[nt], af[mt], acc[mt][nt], 0, 0, 0);
    __builtin_amdgcn_s_setprio(0);
    __builtin_amdgcn_s_waitcnt(0xc07f);  // lgkmcnt(0)
    __builtin_amdgcn_s_barrier();
    if (gi + 3 < nIter) {
      size_t kn = (size_t)(gi + 3) * 4096;
      gld16(At + kn + c0, &L[cur * 4096 + c0]);
      gld16(At + kn + c1, &L[cur * 4096 + c1]);
      gld16(Btl + kn + c0, &L[12288 + cur * 4096 + c0]);
      gld16(Btl + kn + c1, &L[12288 + cur * 4096 + c1]);
    }
  }

  float4 bias4[4];
#pragma unroll
  for (int nt = 0; nt < 4; ++nt) bias4[nt] = *(const float4*)&bias[n0 + wn + nt * 16 + q * 4];

  if (EPI == 0) {
    short* T = L;
#pragma unroll
    for (int mt = 0; mt < 4; ++mt) {
      int ml = wm + mt * 16 + r;
#pragma unroll
      for (int nt = 0; nt < 4; ++nt) {
        f32x4 v = acc[mt][nt];
        v[0] += bias4[nt].x; v[1] += bias4[nt].y; v[2] += bias4[nt].z; v[3] += bias4[nt].w;
        if (z < 2) { v[0] *= v[0]; v[1] *= v[1]; v[2] *= v[2]; v[3] *= v[3]; }
        short4 pk; pk.x = f2bf(v[0]); pk.y = f2bf(v[1]); pk.z = f2bf(v[2]); pk.w = f2bf(v[3]);
        *(short4*)&T[ml * 132 + wn + nt * 16 + q * 4] = pk;
      }
    }
    __syncthreads();
#pragma unroll
    for (int t2 = 0; t2 < 2; ++t2) {
      int task = tid + t2 * 256;
      int row = task & 127, hl = task >> 7;
      size_t obase = ((size_t)((n0 >> 5) + hl) * NROWS + m0 + row) * 32;
#pragma unroll
      for (int j = 0; j < 4; ++j)
        *(bf16x8*)&outz[obase + j * 8] = *(const bf16x8*)&T[row * 132 + hl * 32 + j * 8];
    }
  } else if (EPI == 1) {
#pragma unroll
    for (int mt = 0; mt < 4; ++mt) {
      int ml = wm + mt * 16 + r;
#pragma unroll
      for (int nt = 0; nt < 4; ++nt) {
        f32x4 v = acc[mt][nt];
        v[0] += bias4[nt].x; v[1] += bias4[nt].y; v[2] += bias4[nt].z; v[3] += bias4[nt].w;
#pragma unroll
        for (int e = 0; e < 4; ++e) v[e] = fast_gelu(v[e]);
        short4 o; o.x = f2bf(v[0]); o.y = f2bf(v[1]); o.z = f2bf(v[2]); o.w = f2bf(v[3]);
        int n = n0 + wn + nt * 16 + q * 4;
        size_t ti = ((size_t)blockIdx.x * (N >> 5) + (n >> 5)) * 4096 +
                    (size_t)(((n >> 3) & 3) << 10) + (ml << 3) + (n & 7);
        *(short4*)&outz[ti] = o;
      }
    }
  } else {
    float* TF = (float*)L;
#pragma unroll
    for (int half = 0; half < 2; ++half) {
      __syncthreads();
      if ((w & 1) == half) {
#pragma unroll
        for (int mt = 0; mt < 4; ++mt) {
          int ml = wm + mt * 16 + r;
#pragma unroll
          for (int nt = 0; nt < 4; ++nt) {
            f32x4 v = acc[mt][nt];
            v[0] += bias4[nt].x; v[1] += bias4[nt].y; v[2] += bias4[nt].z; v[3] += bias4[nt].w;
            *(f32x4*)&TF[ml * 68 + nt * 16 + q * 4] = v;
          }
        }
      }
      __syncthreads();
      int row = tid >> 1, col = (tid & 1) * 32;
      size_t hoff = (size_t)(m0 + row) * N + n0 + half * 64 + col;
#pragma unroll
      for (int j = 0; j < 8; ++j) {
        float4 add = *(const float4*)&TF[row * 68 + col + j * 4];
        float4 cur4 = *(float4*)&outf[hoff + j * 4];
        cur4.x += add.x; cur4.y += add.y; cur4.z += add.z; cur4.w += add.w;
        *(float4*)&outf[hoff + j * 4] = cur4;
      }
    }
  }
}

// ---------------- fused FFN: h += gelu(hn@WU+bU)@WV + bV, then LN1[l+1] ------
// R17 structure (1 block/CU, 512 thr, 32 steps, 2x32KB slots), NO setprio.
// Epilogue: TF[128][268] f32 holds h_new; wave w owns rows {p*8+w} for the
// h-RMW (1KB-contiguous), computes LN stats via wave shuffle reduce, then
// writes tiled hn (coalesced 16B x consecutive rows). ln1g==nullptr skips LN.
__global__ __launch_bounds__(512) void ffn_fused(
    const short* __restrict__ A, const short* __restrict__ TUw,
    const short* __restrict__ TVw, const float* __restrict__ bUp,
    const float* __restrict__ bVp, float* __restrict__ h,
    short* __restrict__ hnT, const float* __restrict__ ln1g,
    const float* __restrict__ ln1b) {
  __shared__ __align__(16) short L[81920];  // 160KB
  int tid = threadIdx.x;
  int lane = tid & 63, w = tid >> 6;
  int q = lane >> 4, r = lane & 15;
  int wmU = (w >> 2) * 64, wnU = (w & 3) * 32;   // up: wave = 64 rows x 32 f
  int wmD = (w >> 2) * 64, wnD = (w & 3) * 64;   // down: wave = 64 rows x 64 d
  const short* At = A + (size_t)blockIdx.x * 32768;

  // A strip -> LDS: 64KB contiguous tiled layout (oldest vmem)
#pragma unroll
  for (int i = 0; i < 8; ++i)
    gld16(At + (i * 512 + tid) * 8, &L[(i * 512 + tid) * 8]);

  auto issueFor = [&](int t) {  // stage 32KB slot(t) into buf[t&1]; 4 gld16/thread
    short* dst = &L[49152 + (t & 1) * 16384];
    int ss = t >> 2, pp = t & 3;
    if (pp < 2) {
      const short* g0 = TUw + ((size_t)ss * 8 + pp * 4) * 4096;
#pragma unroll
      for (int i = 0; i < 4; ++i)
        gld16(g0 + (i * 512 + tid) * 8, dst + (i * 512 + tid) * 8);
    } else {
      int kbg0 = ss * 4 + (pp - 2) * 2;
#pragma unroll
      for (int kl = 0; kl < 2; ++kl) {
        gld16(TVw + (size_t)(kbg0 + kl) * 4096 + tid * 8,
              dst + kl * 8192 + tid * 8);
        gld16(TVw + (size_t)(32 + kbg0 + kl) * 4096 + tid * 8,
              dst + kl * 8192 + 4096 + tid * 8);
      }
    }
  };

  issueFor(0); issueFor(1);

  f32x4 vzero = {0.f, 0.f, 0.f, 0.f};
  f32x4 accm[4][2], acco[4][4];
#pragma unroll
  for (int mt = 0; mt < 4; ++mt) {
#pragma unroll
    for (int nt = 0; nt < 2; ++nt) accm[mt][nt] = vzero;
#pragma unroll
    for (int nt = 0; nt < 4; ++nt) acco[mt][nt] = vzero;
  }
  float4 b4[2];

  auto slice = [&](int s, auto lastc) {
    constexpr bool LAST = decltype(lastc)::value;
#pragma unroll
    for (int p = 0; p < 2; ++p) {
      int sig = s * 4 + p;
      __builtin_amdgcn_s_waitcnt(0x0f74);  // vmcnt(4)
      __builtin_amdgcn_s_barrier();
      const short* Ws = &L[49152 + (sig & 1) * 16384];
#pragma unroll
      for (int kl = 0; kl < 4; ++kl) {
        int kb = p * 4 + kl;
        bf16x8 af[4], bfr[2];
#pragma unroll
        for (int mt = 0; mt < 4; ++mt)
          af[mt] = *(const bf16x8*)&L[kb * 4096 + (q * 128 + wmU + mt * 16 + r) * 8];
#pragma unroll
        for (int nt = 0; nt < 2; ++nt)
          bfr[nt] = *(const bf16x8*)&Ws[kl * 4096 + (q * 128 + wnU + nt * 16 + r) * 8];
#pragma unroll
        for (int mt = 0; mt < 4; ++mt)
#pragma unroll
          for (int nt = 0; nt < 2; ++nt)
            accm[mt][nt] = __builtin_amdgcn_mfma_f32_16x16x32_bf16(
                bfr[nt], af[mt], accm[mt][nt], 0, 0, 0);
      }
      if (p == 1) {  // bias + gelu + pack -> mid (A-tile fmt)
#pragma unroll
        for (int mt = 0; mt < 4; ++mt) {
          int row = wmU + mt * 16 + r;
#pragma unroll
          for (int nt = 0; nt < 2; ++nt) {
            f32x4 v = accm[mt][nt];
            float4 bb = b4[nt];
            v[0] += bb.x; v[1] += bb.y; v[2] += bb.z; v[3] += bb.w;
            short4 pk;
            pk.x = f2bf(fast_gelu(v[0])); pk.y = f2bf(fast_gelu(v[1]));
            pk.z = f2bf(fast_gelu(v[2])); pk.w = f2bf(fast_gelu(v[3]));
            int kc8 = 2 * nt + (q >> 1);
            *(short4*)&L[32768 + (w & 3) * 4096 + (kc8 * 128 + row) * 8 + (q & 1) * 4] = pk;
            accm[mt][nt] = vzero;
          }
        }
      }
      __builtin_amdgcn_s_waitcnt(0xc07f);  // lgkmcnt(0)
      __builtin_amdgcn_s_barrier();
      if (p == 0) {
        b4[0] = *(const float4*)&bUp[s * 128 + wnU + q * 4];
        b4[1] = *(const float4*)&bUp[s * 128 + wnU + 16 + q * 4];
      }
      if (sig + 2 < 32) issueFor(sig + 2);
    }
#pragma unroll
    for (int p2 = 0; p2 < 2; ++p2) {
      int sig = s * 4 + 2 + p2;
      if (LAST && p2 == 1) __builtin_amdgcn_s_waitcnt(0x0f70);  // vmcnt(0)
      else                 __builtin_amdgcn_s_waitcnt(0x0f74);  // vmcnt(4)
      __builtin_amdgcn_s_barrier();
      const short* Ws = &L[49152 + (sig & 1) * 16384];
#pragma unroll
      for (int kl = 0; kl < 2; ++kl) {
        int mtile = p2 * 2 + kl;
        bf16x8 am[4], bvf[4];
#pragma unroll
        for (int mt = 0; mt < 4; ++mt)
          am[mt] = *(const bf16x8*)&L[32768 + mtile * 4096 + (q * 128 + wmD + mt * 16 + r) * 8];
#pragma unroll
        for (int nt = 0; nt < 4; ++nt)
          bvf[nt] = *(const bf16x8*)&Ws[kl * 8192 + (wnD >> 7) * 4096 +
                                        (q * 128 + (wnD & 127) + nt * 16 + r) * 8];
#pragma unroll
        for (int mt = 0; mt < 4; ++mt)
#pragma unroll
          for (int nt = 0; nt < 4; ++nt)
            acco[mt][nt] = __builtin_amdgcn_mfma_f32_16x16x32_bf16(
                bvf[nt], am[mt], acco[mt][nt], 0, 0, 0);
      }
      __builtin_amdgcn_s_waitcnt(0xc07f);  // lgkmcnt(0)
      __builtin_amdgcn_s_barrier();
      if (sig + 2 < 32) issueFor(sig + 2);
    }
  };

  for (int s = 0; s < 7; ++s) slice(s, FalseT{});
  slice(7, TrueT{});

  // ---- epilogue: out += bV; TF[128][268]; wave-owns-row h RMW + fused LN1 ----
  float* TF = (float*)L;                     // [128][268] f32 = 137,216B
  float* MEAN = (float*)&L[68608];           // byte 137,216
  float* RSTD = MEAN + 128;
  float4 bv4[4];
#pragma unroll
  for (int nt = 0; nt < 4; ++nt) bv4[nt] = *(const float4*)&bVp[wnD + nt * 16 + q * 4];
#pragma unroll
  for (int mt = 0; mt < 4; ++mt) {
    int row = wmD + mt * 16 + r;
#pragma unroll
    for (int nt = 0; nt < 4; ++nt) {
      f32x4 v = acco[mt][nt];
      v[0] += bv4[nt].x; v[1] += bv4[nt].y; v[2] += bv4[nt].z; v[3] += bv4[nt].w;
      *(f32x4*)&TF[row * 268 + wnD + nt * 16 + q * 4] = v;
    }
  }
  __syncthreads();
  // h RMW: wave w owns rows {p*8+w}; lanes cover full 1KB row contiguously
#pragma unroll
  for (int p = 0; p < 16; ++p) {
    int row = p * 8 + w;
    int col = lane * 4;
    size_t off = ((size_t)blockIdx.x * 128 + row) * DD + col;
    float4 ad = *(const float4*)&TF[row * 268 + col];
    float4 cv = *(float4*)&h[off];
    cv.x += ad.x; cv.y += ad.y; cv.z += ad.z; cv.w += ad.w;
    *(float4*)&h[off] = cv;
    if (ln1g) {
      *(float4*)&TF[row * 268 + col] = cv;   // stage h_new for the hn pass
      float s = cv.x + cv.y + cv.z + cv.w;
      float s2 = cv.x * cv.x + cv.y * cv.y + cv.z * cv.z + cv.w * cv.w;
      s += __shfl_xor(s, 1); s += __shfl_xor(s, 2); s += __shfl_xor(s, 4);
      s += __shfl_xor(s, 8); s += __shfl_xor(s, 16); s += __shfl_xor(s, 32);
      s2 += __shfl_xor(s2, 1); s2 += __shfl_xor(s2, 2); s2 += __shfl_xor(s2, 4);
      s2 += __shfl_xor(s2, 8); s2 += __shfl_xor(s2, 16); s2 += __shfl_xor(s2, 32);
      if (lane == 0) {
        float mn = s * (1.0f / 256.0f);
        MEAN[row] = mn;
        RSTD[row] = rsqrtf(s2 * (1.0f / 256.0f) - mn * mn + 1e-5f);
      }
    }
  }
  if (ln1g) {
    __syncthreads();
    int row2 = tid & 127, kc8g = tid >> 7;
    float mn = MEAN[row2], rstd = RSTD[row2];
    short* tb = hnT + (size_t)blockIdx.x * 32768 + (kc8g * 128 + row2) * 8;
#pragma unroll
    for (int kb = 0; kb < 8; ++kb) {
      int k0 = kb * 32 + kc8g * 8;
      float4 x0 = *(const float4*)&TF[row2 * 268 + k0];
      float4 x1 = *(const float4*)&TF[row2 * 268 + k0 + 4];
      float4 g0 = *(const float4*)&ln1g[k0], g1 = *(const float4*)&ln1g[k0 + 4];
      float4 b0 = *(const float4*)&ln1b[k0], b1 = *(const float4*)&ln1b[k0 + 4];
      bf16x8 aw;
      aw[0] = f2bf((x0.x - mn) * rstd * g0.x + b0.x);
      aw[1] = f2bf((x0.y - mn) * rstd * g0.y + b0.y);
      aw[2] = f2bf((x0.z - mn) * rstd * g0.z + b0.z);
      aw[3] = f2bf((x0.w - mn) * rstd * g0.w + b0.w);
      aw[4] = f2bf((x1.x - mn) * rstd * g1.x + b1.x);
      aw[5] = f2bf((x1.y - mn) * rstd * g1.y + b1.y);
      aw[6] = f2bf((x1.z - mn) * rstd * g1.z + b1.z);
      aw[7] = f2bf((x1.w - mn) * rstd * g1.w + b1.w);
      *(bf16x8*)&tb[(size_t)kb * 4096] = aw;
    }
  }
}

// ---------------- attention A1: per (b,h,chunk) S_c = K^T V, z_c = sum k ------
__global__ __launch_bounds__(256) void attn_chunk_kv(
    const short* __restrict__ Kb, const short* __restrict__ Vb,
    float* __restrict__ St, float* __restrict__ Zc) {
  __shared__ short Kt[4][32 * 72];
  __shared__ short Vt[4][32 * 72];
  int wid = threadIdx.x >> 6;
  int blk = blockIdx.x * 4 + wid;
  int c = blk & (NC - 1), bh = blk >> 5;
  int b = bh >> 3, hh = bh & 7;
  int lane = threadIdx.x & 63, q = lane >> 4, r = lane & 15;
  size_t rowbase = ((size_t)hh * NROWS + b * GG + c * CS + lane) * 32;
#pragma unroll
  for (int j = 0; j < 4; ++j) {
    bf16x8 kv = *(const bf16x8*)&Kb[rowbase + j * 8];
    bf16x8 vv = *(const bf16x8*)&Vb[rowbase + j * 8];
#pragma unroll
    for (int e = 0; e < 8; ++e) {
      Kt[wid][(j * 8 + e) * 72 + lane] = kv[e];
      Vt[wid][(j * 8 + e) * 72 + lane] = vv[e];
    }
  }
  __syncthreads();
  f32x4 vzero = {0.f, 0.f, 0.f, 0.f};
  f32x4 acc[2][2];
#pragma unroll
  for (int i = 0; i < 2; ++i)
#pragma unroll
    for (int j = 0; j < 2; ++j) acc[i][j] = vzero;
#pragma unroll
  for (int ks = 0; ks < 2; ++ks) {
    bf16x8 afr[2], bfr[2];
#pragma unroll
    for (int mt = 0; mt < 2; ++mt) afr[mt] = *(const bf16x8*)&Kt[wid][(mt * 16 + r) * 72 + ks * 32 + q * 8];
#pragma unroll
    for (int nt = 0; nt < 2; ++nt) bfr[nt] = *(const bf16x8*)&Vt[wid][(nt * 16 + r) * 72 + ks * 32 + q * 8];
#pragma unroll
    for (int mt = 0; mt < 2; ++mt)
#pragma unroll
      for (int nt = 0; nt < 2; ++nt)
        acc[mt][nt] = __builtin_amdgcn_mfma_f32_16x16x32_bf16(afr[mt], bfr[nt], acc[mt][nt], 0, 0, 0);
  }
  float* stp = St + ((size_t)bh * NC + c) * 1024;
#pragma unroll
  for (int mt = 0; mt < 2; ++mt)
#pragma unroll
    for (int nt = 0; nt < 2; ++nt)
      *(f32x4*)&stp[(nt * 16 + r) * 32 + mt * 16 + q * 4] = acc[mt][nt];  // St[d][f]
  if (lane < 32) {
    float s = 0.f;
#pragma unroll
    for (int j = 0; j < 8; ++j) {
      bf16x8 kr = *(const bf16x8*)&Kt[wid][lane * 72 + j * 8];
#pragma unroll
      for (int e = 0; e < 8; ++e) s += bf2f(kr[e]);
    }
    Zc[((size_t)bh * NC + c) * 32 + lane] = s;
  }
}

// ---------------- attention A2: exclusive prefix over chunks ------------------
__global__ __launch_bounds__(1024) void attn_prefix(float* __restrict__ St, float* __restrict__ Zc) {
  int bh = blockIdx.x, i = threadIdx.x;
  float run = 0.f;
  float* p = St + (size_t)bh * NC * 1024 + i;
#pragma unroll
  for (int c = 0; c < NC; ++c) { float t = p[(size_t)c * 1024]; p[(size_t)c * 1024] = run; run += t; }
  if (i < 32) {
    float rz = 0.f;
    float* pz = Zc + (size_t)bh * NC * 32 + i;
#pragma unroll
    for (int c = 0; c < NC; ++c) { float t = pz[c * 32]; pz[c * 32] = rz; rz += t; }
  }
}

// ---------------- attention B: intra-chunk + apply + fused LN2 ---------------
// Block = (b, c): 8 waves = 8 heads of the SAME 64-row chunk. Epilogue holds
// full 256-col rows -> h RMW (wave-owns-row, 1KB contiguous) + LN2 stats via
// wave shuffle + tiled hn write. 512 thr, 113KB LDS (1 block/CU, 8 waves).
__global__ __launch_bounds__(512) void attn_intra(
    const short* __restrict__ Qb, const short* __restrict__ Kb,
    const short* __restrict__ Vb, const float* __restrict__ St,
    const float* __restrict__ Zc, float* __restrict__ h,
    short* __restrict__ hnT, const float* __restrict__ ln2g,
    const float* __restrict__ ln2b) {
  __shared__ __align__(16) short P[8][64 * 72];   // 73,728B; aliased as OF later
  __shared__ short Vt[8][32 * 72];                 // 36,864B
  __shared__ float den[8][64];
  __shared__ float MEAN[64], RSTD[64];
  int wid = threadIdx.x >> 6;   // head 0..7
  int u = blockIdx.x;
  int b = u >> 5, c = u & 31;
  int hh = wid, bh = b * 8 + hh;
  int lane = threadIdx.x & 63, q = lane >> 4, r = lane & 15;
  size_t hrow0 = (size_t)b * GG + c * CS;
  size_t qrow0 = (size_t)hh * NROWS + b * GG + c * CS;

  const float* zp = Zc + ((size_t)bh * NC + c) * 32;
  float qz = 0.f;
  {
    size_t qoff = (qrow0 + lane) * 32;
#pragma unroll
    for (int j = 0; j < 4; ++j) {
      bf16x8 qv = *(const bf16x8*)&Qb[qoff + j * 8];
#pragma unroll
      for (int e = 0; e < 8; ++e) qz += bf2f(qv[e]) * zp[j * 8 + e];
    }
  }
  den[wid][lane] = qz;

  {
    size_t voff = (qrow0 + lane) * 32;
#pragma unroll
    for (int j = 0; j < 4; ++j) {
      bf16x8 vv = *(const bf16x8*)&Vb[voff + j * 8];
#pragma unroll
      for (int e = 0; e < 8; ++e) Vt[wid][(j * 8 + e) * 72 + lane] = vv[e];
    }
  }

  bf16x8 ak[4], bqf[4];
#pragma unroll
  for (int t4 = 0; t4 < 4; ++t4) {
    ak[t4]  = *(const bf16x8*)&Kb[(qrow0 + t4 * 16 + r) * 32 + q * 8];
    bqf[t4] = *(const bf16x8*)&Qb[(qrow0 + t4 * 16 + r) * 32 + q * 8];
  }
  f32x4 vzero = {0.f, 0.f, 0.f, 0.f};
  f32x4 pacc[4][4];
#pragma unroll
  for (int mt = 0; mt < 4; ++mt)
#pragma unroll
    for (int nt = 0; nt < 4; ++nt)
      pacc[mt][nt] = __builtin_amdgcn_mfma_f32_16x16x32_bf16(ak[mt], bqf[nt], vzero, 0, 0, 0);

  float rs[4] = {0.f, 0.f, 0.f, 0.f};
#pragma unroll
  for (int nt = 0; nt < 4; ++nt) {
    int t = nt * 16 + r;
#pragma unroll
    for (int mt = 0; mt < 4; ++mt) {
      short4 pk;
#pragma unroll
      for (int rr = 0; rr < 4; ++rr) {
        int s = mt * 16 + q * 4 + rr;
        float pv = (s <= t) ? pacc[mt][nt][rr] : 0.f;
        rs[nt] += pv;
        ((short*)&pk)[rr] = f2bf(pv);
      }
      *(short4*)&P[wid][t * 72 + mt * 16 + q * 4] = pk;
    }
  }
#pragma unroll
  for (int nt = 0; nt < 4; ++nt) {
    rs[nt] += __shfl_xor(rs[nt], 16);
    rs[nt] += __shfl_xor(rs[nt], 32);
  }
  __syncthreads();
  if (lane < 16) {
#pragma unroll
    for (int nt = 0; nt < 4; ++nt) den[wid][nt * 16 + lane] += rs[nt];
  }
  __syncthreads();

  f32x4 oacc[4][2];
#pragma unroll
  for (int mt = 0; mt < 4; ++mt)
#pragma unroll
    for (int nt2 = 0; nt2 < 2; ++nt2) oacc[mt][nt2] = vzero;
  const float* stp = St + ((size_t)bh * NC + c) * 1024;
#pragma unroll
  for (int nt2 = 0; nt2 < 2; ++nt2) {
    float4 s0 = *(const float4*)&stp[(nt2 * 16 + r) * 32 + q * 8];
    float4 s1 = *(const float4*)&stp[(nt2 * 16 + r) * 32 + q * 8 + 4];
    bf16x8 bs;
    bs[0] = f2bf(s0.x); bs[1] = f2bf(s0.y); bs[2] = f2bf(s0.z); bs[3] = f2bf(s0.w);
    bs[4] = f2bf(s1.x); bs[5] = f2bf(s1.y); bs[6] = f2bf(s1.z); bs[7] = f2bf(s1.w);
#pragma unroll
    for (int mt = 0; mt < 4; ++mt)
      oacc[mt][nt2] = __builtin_amdgcn_mfma_f32_16x16x32_bf16(bqf[mt], bs, oacc[mt][nt2], 0, 0, 0);
  }
#pragma unroll
  for (int ks = 0; ks < 2; ++ks) {
    bf16x8 ap[4];
#pragma unroll
    for (int mt = 0; mt < 4; ++mt)
      ap[mt] = *(const bf16x8*)&P[wid][(mt * 16 + r) * 72 + ks * 32 + q * 8];
#pragma unroll
    for (int nt2 = 0; nt2 < 2; ++nt2) {
      bf16x8 bv_ = *(const bf16x8*)&Vt[wid][(nt2 * 16 + r) * 72 + ks * 32 + q * 8];
#pragma unroll
      for (int mt = 0; mt < 4; ++mt)
        oacc[mt][nt2] = __builtin_amdgcn_mfma_f32_16x16x32_bf16(ap[mt], bv_, oacc[mt][nt2], 0, 0, 0);
    }
  }

  // ---- epilogue: OF[64][268] f32 (aliases P); h RMW + LN2 + tiled hn ----
  float* OF = (float*)&P[0][0];   // 64*268*4 = 68,608B <= 73,728B
  __syncthreads();                // all waves done reading P
#pragma unroll
  for (int mt = 0; mt < 4; ++mt) {
#pragma unroll
    for (int rr = 0; rr < 4; ++rr) {
      int t = mt * 16 + q * 4 + rr;
      float inv = 1.0f / (den[wid][t] + 1e-16f);
#pragma unroll
      for (int nt2 = 0; nt2 < 2; ++nt2)
        OF[t * 268 + hh * 32 + nt2 * 16 + r] = oacc[mt][nt2][rr] * inv;
    }
  }
  __syncthreads();
  int tid = threadIdx.x;
#pragma unroll
  for (int p = 0; p < 8; ++p) {
    int row = p * 8 + wid;
    int col = lane * 4;
    size_t off = (hrow0 + row) * DD + col;
    float4 ad = *(const float4*)&OF[row * 268 + col];
    float4 cv = *(float4*)&h[off];
    cv.x += ad.x; cv.y += ad.y; cv.z += ad.z; cv.w += ad.w;
    *(float4*)&h[off] = cv;
    *(float4*)&OF[row * 268 + col] = cv;    // stage h_new for the hn pass
    float s = cv.x + cv.y + cv.z + cv.w;
    float s2 = cv.x * cv.x + cv.y * cv.y + cv.z * cv.z + cv.w * cv.w;
    s += __shfl_xor(s, 1); s += __shfl_xor(s, 2); s += __shfl_xor(s, 4);
    s += __shfl_xor(s, 8); s += __shfl_xor(s, 16); s += __shfl_xor(s, 32);
    s2 += __shfl_xor(s2, 1); s2 += __shfl_xor(s2, 2); s2 += __shfl_xor(s2, 4);
    s2 += __shfl_xor(s2, 8); s2 += __shfl_xor(s2, 16); s2 += __shfl_xor(s2, 32);
    if (lane == 0) {
      float mn = s * (1.0f / 256.0f);
      MEAN[row] = mn;
      RSTD[row] = rsqrtf(s2 * (1.0f / 256.0f) - mn * mn + 1e-5f);
    }
  }
  __syncthreads();
  int row2 = tid & 63, kc8g = (tid >> 6) & 3, half = tid >> 8;
  float mn = MEAN[row2], rstd = RSTD[row2];
  size_t grow = hrow0 + row2;
  short* tb = hnT + (grow >> 7) * 32768 + (kc8g * 128 + (int)(grow & 127)) * 8;
#pragma unroll
  for (int j = 0; j < 4; ++j) {
    int kb = half * 4 + j;
    int k0 = kb * 32 + kc8g * 8;
    float4 x0 = *(const float4*)&OF[row2 * 268 + k0];
    float4 x1 = *(const float4*)&OF[row2 * 268 + k0 + 4];
    float4 g0 = *(const float4*)&ln2g[k0], g1 = *(const float4*)&ln2g[k0 + 4];
    float4 b0 = *(const float4*)&ln2b[k0], b1 = *(const float4*)&ln2b[k0 + 4];
    bf16x8 aw;
    aw[0] = f2bf((x0.x - mn) * rstd * g0.x + b0.x);
    aw[1] = f2bf((x0.y - mn) * rstd * g0.y + b0.y);
    aw[2] = f2bf((x0.z - mn) * rstd * g0.z + b0.z);
    aw[3] = f2bf((x0.w - mn) * rstd * g0.w + b0.w);
    aw[4] = f2bf((x1.x - mn) * rstd * g1.x + b1.x);
    aw[5] = f2bf((x1.y - mn) * rstd * g1.y + b1.y);
    aw[6] = f2bf((x1.z - mn) * rstd * g1.z + b1.z);
    aw[7] = f2bf((x1.w - mn) * rstd * g1.w + b1.w);
    *(bf16x8*)&tb[(size_t)kb * 4096] = aw;
  }
}

// ---------------- final projection -------------------------------------------
__global__ __launch_bounds__(256) void out_proj(
    const float* __restrict__ h, const float* __restrict__ Wout,
    const float* __restrict__ bout, float* __restrict__ out) {
  int row = blockIdx.x * 4 + (threadIdx.x >> 6);
  int lane = threadIdx.x & 63;
  float4 a = *(const float4*)&h[(size_t)row * DD + lane * 4];
  float4 w = *(const float4*)&Wout[lane * 4];
  float s = a.x * w.x + a.y * w.y + a.z * w.z + a.w * w.w;
#pragma unroll
  for (int o = 1; o < 64; o <<= 1) s += __shfl_xor(s, o);
  if (lane == 0) out[row] = s + bout[0];
}

extern "C" void kernel_launch(void* const* d_in, const int* in_sizes, int n_in,
                              void* d_out, int out_size, void* d_ws, size_t ws_size,
                              hipStream_t stream) {
  const float* x    = (const float*)d_in[0];
  const float* ge   = (const float*)d_in[1];
  const float* invf = (const float*)d_in[2];
  const float* Wq   = (const float*)d_in[3];
  const float* bq   = (const float*)d_in[4];
  const float* Wk   = (const float*)d_in[5];
  const float* bk   = (const float*)d_in[6];
  const float* Wv   = (const float*)d_in[7];
  const float* bv   = (const float*)d_in[8];
  const float* ln1g = (const float*)d_in[9];
  const float* ln1b = (const float*)d_in[10];
  const float* ln2g = (const float*)d_in[11];
  const float* ln2b = (const float*)d_in[12];
  const float* WU   = (const float*)d_in[13];
  const float* bU   = (const float*)d_in[14];
  const float* WV   = (const float*)d_in[15];
  const float* bV   = (const float*)d_in[16];
  const float* Wout = (const float*)d_in[17];
  const float* bout = (const float*)d_in[18];
  float* out = (float*)d_out;

  char* ws = (char*)d_ws;
  float* h   = (float*)(ws + 0);            // 33.5 MB
  short* hn  = (short*)(ws + 33554432);     // 16.8 MB (tiled)
  char*  R   = ws + 50331648;               // shared region
  short* qb  = (short*)(R + 0);             // head-major [8][32768][32]
  short* kb  = (short*)(R + 16777216);
  short* vb  = (short*)(R + 33554432);
  float* St  = (float*)(R + 50331648);
  float* Zc  = (float*)(R + 67108864);
  char*  WT  = R + 67633152;
  short* TQ  = (short*)(WT + 0);
  short* TK  = (short*)(WT + 524288);
  short* TVq = (short*)(WT + 1048576);
  short* TU  = (short*)(WT + 1572864);
  short* TVd = (short*)(WT + 3670016);

  prep_weights<<<dim3(1024, 4, 5), 256, 0, stream>>>(Wq, Wk, Wv, WU, WV, TQ, TK, TVq, TU, TVd);
  embed_kernel<<<NROWS / 4, 256, 0, stream>>>(x, ge, invf, h);
  ln_tiled<<<NROWS / 32, 256, 0, stream>>>(h, ln1g, ln1b, hn);  // layer-0 LN1

  for (int l = 0; l < 4; ++l) {
    gemm_t<256, 0><<<dim3(256, 2, 3), 256, 0, stream>>>(
        hn, TQ + l * 65536, TK + l * 65536, TVq + l * 65536,
        bq + l * 256, bk + l * 256, bv + l * 256,
        qb, kb, vb, nullptr, 256);
    attn_chunk_kv<<<1024, 256, 0, stream>>>(kb, vb, St, Zc);
    attn_prefix<<<128, 1024, 0, stream>>>(St, Zc);
    attn_intra<<<512, 512, 0, stream>>>(qb, kb, vb, St, Zc, h,
                                        hn, ln2g + l * 256, ln2b + l * 256);
    ffn_fused<<<256, 512, 0, stream>>>(hn, TU + l * 262144, TVd + l * 262144,
                                       bU + l * 1024, bV + l * 256, h,
                                       hn,
                                       (l < 3) ? ln1g + (l + 1) * 256 : nullptr,
                                       (l < 3) ? ln1b + (l + 1) * 256 : nullptr);
  }
  out_proj<<<NROWS / 4, 256, 0, stream>>>(h, Wout, bout, out);
}